// Round 5
// baseline (1331.043 us; speedup 1.0000x reference)
//
#include <hip/hip_runtime.h>
#include <math.h>

#define NVOX 65536
#define DM 256
#define NH 8
#define HDIM 32
#define DFFN 2048
#define SSZ 128
#define SNUM 512

#define AS1 __attribute__((address_space(1)))
#define AS3 __attribute__((address_space(3)))

typedef __attribute__((ext_vector_type(8))) __bf16 bf16x8;
typedef __attribute__((ext_vector_type(8))) unsigned short u16x8;
typedef __attribute__((ext_vector_type(4))) float f32x4;

__device__ __forceinline__ unsigned short f2bf(float f) {
    unsigned int u = __float_as_uint(f);
    u += 0x7fffu + ((u >> 16) & 1u);
    return (unsigned short)(u >> 16);
}
__device__ __forceinline__ float bf2f(unsigned short u) {
    return __uint_as_float(((unsigned int)u) << 16);
}

// ===================== weight fp32 -> bf16 ========================
__global__ __launch_bounds__(256)
void cvt_bf16_kernel(const float* __restrict__ in, unsigned short* __restrict__ out, int n) {
    int i = blockIdx.x * 256 + threadIdx.x;
    int stride = gridDim.x * 256;
    for (; i < n; i += stride) out[i] = f2bf(in[i]);
}

// ============================= gather =============================
__global__ __launch_bounds__(256)
void gather_kernel(const float* __restrict__ src, const float* __restrict__ pos,
                   const int* __restrict__ inds,
                   unsigned short* __restrict__ qk, unsigned short* __restrict__ feat) {
    int j = blockIdx.x * 4 + (threadIdx.x >> 6);
    int lane = threadIdx.x & 63;
    int v = inds[j];
    float4 a = ((const float4*)(src + (size_t)v * DM))[lane];
    float4 p = ((const float4*)(pos + (size_t)v * DM))[lane];
    ushort4 qo, fo;
    qo.x = f2bf(a.x + p.x); qo.y = f2bf(a.y + p.y);
    qo.z = f2bf(a.z + p.z); qo.w = f2bf(a.w + p.w);
    fo.x = f2bf(a.x); fo.y = f2bf(a.y); fo.z = f2bf(a.z); fo.w = f2bf(a.w);
    ((ushort4*)(qk   + (size_t)j * DM))[lane] = qo;
    ((ushort4*)(feat + (size_t)j * DM))[lane] = fo;
}

// ========================= bf16 MFMA GEMM =========================
// C[M,N] = A[M,K](bf16) @ W[N,K](bf16)^T + bias[N](f32); opt ReLU; out f32/bf16.
// 128x128 tile, BK=32, 4 waves (2x2), 16x16x32 MFMA.
// v3: LDS holds tiles in MFMA *fragment order* (sub-tile st at st*1KB,
//     lane-linear 16B) via per-lane global_load_lds source addresses
//     -> ds_read_b128 at tileBase+lane*16: ZERO bank conflicts.
//     Double-buffered prefetch K-loop + LDS-staged vectorized epilogue.
template<bool RELU, bool OBF16>
__global__ __launch_bounds__(256)
void gemm_mfma(const unsigned short* __restrict__ A, const unsigned short* __restrict__ W,
               const float* __restrict__ bias, void* __restrict__ Cout,
               int M, int N, int K) {
    // LDS: dbuf As[2][4096] u16 (16KB) + Bs[2][4096] u16 (16KB) = 32KB,
    // epilogue f32 strip (32x132) aliased on top after the K-loop.
    __shared__ alignas(16) char smem[32768];
    unsigned short* As = (unsigned short*)smem;           // buf b at b*4096
    unsigned short* Bs = (unsigned short*)(smem + 16384); // buf b at b*4096
    float* ebuf = (float*)smem;
    const int ESTRIDE = 132;

    int tid = threadIdx.x;
    int wave = tid >> 6, lane = tid & 63;
    int waveM = wave >> 1, waveN = wave & 1;
    int mBase = blockIdx.x * 128, nBase = blockIdx.y * 128;

    f32x4 acc[4][4];
    const f32x4 zero = {0.f, 0.f, 0.f, 0.f};
#pragma unroll
    for (int i = 0; i < 4; i++)
#pragma unroll
        for (int j = 0; j < 4; j++) acc[i][j] = zero;

    int rr = lane & 15;          // fragment row (within 16-row sub-tile)
    int kh = (lane >> 4) * 8;    // fragment k-offset (elems)
    int rbase = (lane >> 4) * 4;

    // stage sub-tile st (16 rows x 32 k) in fragment order:
    // lane l sources A[st*16 + (l&15)][k0 + (l>>4)*8 .. +7] (16B contiguous),
    // LDS dest = st*512 elems + l*8 elems (lane-linear, HW-enforced).
    auto stage = [&](int b, int k0) {
#pragma unroll
        for (int u = 0; u < 2; ++u) {
            int st = wave * 2 + u;  // sub-tile 0..7
            const unsigned short* ga = A + (size_t)(mBase + st * 16 + rr) * K + k0 + kh;
            __builtin_amdgcn_global_load_lds((const AS1 void*)ga,
                (AS3 void*)(As + b * 4096 + st * 512), 16, 0, 0);
            const unsigned short* gb = W + (size_t)(nBase + st * 16 + rr) * K + k0 + kh;
            __builtin_amdgcn_global_load_lds((const AS1 void*)gb,
                (AS3 void*)(Bs + b * 4096 + st * 512), 16, 0, 0);
        }
    };

    int nt = K >> 5;
    stage(0, 0);
    __syncthreads();

    int cur = 0;
    for (int t = 0; t < nt; ++t) {
        if (t + 1 < nt) stage(cur ^ 1, (t + 1) << 5);

        bf16x8 af[4], bfr[4];
#pragma unroll
        for (int i = 0; i < 4; i++)
            af[i] = *(const bf16x8*)(As + cur * 4096 + (waveM * 4 + i) * 512 + lane * 8);
#pragma unroll
        for (int j = 0; j < 4; j++)
            bfr[j] = *(const bf16x8*)(Bs + cur * 4096 + (waveN * 4 + j) * 512 + lane * 8);
#pragma unroll
        for (int i = 0; i < 4; i++)
#pragma unroll
            for (int j = 0; j < 4; j++)
                acc[i][j] = __builtin_amdgcn_mfma_f32_16x16x32_bf16(af[i], bfr[j], acc[i][j], 0, 0, 0);

        if (t + 1 < nt) {
            __syncthreads();  // compiler-emitted vmcnt(0) completes prefetch
            cur ^= 1;
        }
    }

    // ---- epilogue: 4 passes of 32 rows via LDS, vectorized stores ----
    float bn[4];
#pragma unroll
    for (int j = 0; j < 4; j++)
        bn[j] = bias[nBase + waveN * 64 + j * 16 + rr];

    int erow = tid >> 3;              // 0..31
    int ecol = (tid & 7) * 16;        // 0..112
#pragma unroll
    for (int ph = 0; ph < 4; ++ph) {
        __syncthreads();  // pass 0: also protects LDS reuse after K-loop
        if (waveM == (ph >> 1)) {
#pragma unroll
            for (int ii = 0; ii < 2; ++ii) {
                int i = (ph & 1) * 2 + ii;
#pragma unroll
                for (int j = 0; j < 4; ++j) {
                    int lcol = waveN * 64 + j * 16 + rr;
#pragma unroll
                    for (int r = 0; r < 4; ++r) {
                        float v = acc[i][j][r] + bn[j];
                        if (RELU) v = fmaxf(v, 0.f);
                        ebuf[(ii * 16 + rbase + r) * ESTRIDE + lcol] = v;
                    }
                }
            }
        }
        __syncthreads();
        int grow = mBase + ph * 32 + erow;
        if (OBF16) {
            u16x8 o0, o1;
#pragma unroll
            for (int g = 0; g < 8; ++g) {
                o0[g] = f2bf(ebuf[erow * ESTRIDE + ecol + g]);
                o1[g] = f2bf(ebuf[erow * ESTRIDE + ecol + 8 + g]);
            }
            u16x8* dst = (u16x8*)((unsigned short*)Cout + (size_t)grow * N + nBase + ecol);
            dst[0] = o0;
            dst[1] = o1;
        } else {
            float* dst = (float*)Cout + (size_t)grow * N + nBase + ecol;
#pragma unroll
            for (int g = 0; g < 4; ++g)
                *(float4*)(dst + g * 4) = *(float4*)(ebuf + erow * ESTRIDE + ecol + g * 4);
        }
    }
}

// ======================= MFMA attention ===========================
__global__ __launch_bounds__(256)
void attn_mfma_kernel(const unsigned short* __restrict__ QK,
                      const unsigned short* __restrict__ V,
                      const unsigned char* __restrict__ mask,
                      unsigned short* __restrict__ ao) {
    int s = blockIdx.x, h = blockIdx.y;
    int tid = threadIdx.x;
    int wq = tid >> 6;
    int lane = tid & 63;

    __shared__ alignas(16) unsigned short Ks[128 * 40];
    __shared__ alignas(16) unsigned short Vt[32 * 136];
    __shared__ alignas(16) unsigned short Plds[4 * 4096];
    __shared__ unsigned char msk[SSZ];

#pragma unroll
    for (int it = 0; it < 2; it++) {
        int idx = tid + it * 256;
        int key = idx >> 2, dimoff = (idx & 3) * 8;
        bf16x8 kv = *(const bf16x8*)(QK + (size_t)(s * SSZ + key) * 512 + 256 + h * HDIM + dimoff);
        *(bf16x8*)(Ks + key * 40 + dimoff) = kv;
        u16x8 vv = *(const u16x8*)(V + (size_t)(s * SSZ + key) * DM + h * HDIM + dimoff);
#pragma unroll
        for (int j = 0; j < 8; j++) Vt[(dimoff + j) * 136 + key] = vv[j];
    }
    if (tid < SSZ) msk[tid] = mask[s * SSZ + tid];
    __syncthreads();

    int rr = lane & 15;
    int kq = (lane >> 4) * 8;
    const f32x4 zero = {0.f, 0.f, 0.f, 0.f};

    bf16x8 qa[2];
#pragma unroll
    for (int mt = 0; mt < 2; mt++)
        qa[mt] = *(const bf16x8*)(QK + (size_t)(s * SSZ + wq * 32 + mt * 16 + rr) * 512 + h * HDIM + kq);

    f32x4 S[2][8];
#pragma unroll
    for (int nt = 0; nt < 8; nt++) {
        bf16x8 kb = *(const bf16x8*)(Ks + (nt * 16 + rr) * 40 + kq);
#pragma unroll
        for (int mt = 0; mt < 2; mt++)
            S[mt][nt] = __builtin_amdgcn_mfma_f32_16x16x32_bf16(qa[mt], kb, zero, 0, 0, 0);
    }

    const float SCALE = 0.17677669529663687f;
    f32x4 rm[2];
#pragma unroll
    for (int mt = 0; mt < 2; mt++) { rm[mt].x = rm[mt].y = rm[mt].z = rm[mt].w = -1e30f; }
#pragma unroll
    for (int nt = 0; nt < 8; nt++) {
        bool mv = msk[nt * 16 + rr] != 0;
#pragma unroll
        for (int mt = 0; mt < 2; mt++) {
#pragma unroll
            for (int r = 0; r < 4; r++) {
                float v = mv ? -1e30f : S[mt][nt][r] * SCALE;
                S[mt][nt][r] = v;
                rm[mt][r] = fmaxf(rm[mt][r], v);
            }
        }
    }
#pragma unroll
    for (int off = 1; off < 16; off <<= 1) {
#pragma unroll
        for (int mt = 0; mt < 2; mt++)
#pragma unroll
            for (int r = 0; r < 4; r++)
                rm[mt][r] = fmaxf(rm[mt][r], __shfl_xor(rm[mt][r], off));
    }

    f32x4 rs[2];
#pragma unroll
    for (int mt = 0; mt < 2; mt++) { rs[mt] = zero; }
#pragma unroll
    for (int nt = 0; nt < 8; nt++)
#pragma unroll
        for (int mt = 0; mt < 2; mt++)
#pragma unroll
            for (int r = 0; r < 4; r++) {
                float p = __expf(S[mt][nt][r] - rm[mt][r]);
                S[mt][nt][r] = p;
                rs[mt][r] += p;
            }
#pragma unroll
    for (int off = 1; off < 16; off <<= 1) {
#pragma unroll
        for (int mt = 0; mt < 2; mt++)
#pragma unroll
            for (int r = 0; r < 4; r++)
                rs[mt][r] += __shfl_xor(rs[mt][r], off);
    }

    char* Pbase = (char*)Plds + wq * 8192;
#pragma unroll
    for (int nt = 0; nt < 8; nt++)
#pragma unroll
        for (int mt = 0; mt < 2; mt++)
#pragma unroll
            for (int r = 0; r < 4; r++) {
                int prow = mt * 16 + (lane >> 4) * 4 + r;
                int col  = nt * 16 + rr;
                unsigned addr = (unsigned)(prow * 256 + col * 2) ^ ((prow & 7) << 4);
                *(unsigned short*)(Pbase + addr) = f2bf(S[mt][nt][r]);
            }
    __syncthreads();

    f32x4 O[2][2];
#pragma unroll
    for (int mt = 0; mt < 2; mt++)
#pragma unroll
        for (int nd = 0; nd < 2; nd++) O[mt][nd] = zero;
#pragma unroll
    for (int kc = 0; kc < 4; kc++) {
        bf16x8 pa[2];
#pragma unroll
        for (int mt = 0; mt < 2; mt++) {
            int prow = mt * 16 + rr;
            unsigned addr = (unsigned)(prow * 256 + (kc * 32 + kq) * 2) ^ ((prow & 7) << 4);
            pa[mt] = *(const bf16x8*)(Pbase + addr);
        }
#pragma unroll
        for (int nd = 0; nd < 2; nd++) {
            bf16x8 vb = *(const bf16x8*)(Vt + (nd * 16 + rr) * 136 + kc * 32 + kq);
#pragma unroll
            for (int mt = 0; mt < 2; mt++)
                O[mt][nd] = __builtin_amdgcn_mfma_f32_16x16x32_bf16(pa[mt], vb, O[mt][nd], 0, 0, 0);
        }
    }

#pragma unroll
    for (int mt = 0; mt < 2; mt++) {
#pragma unroll
        for (int nd = 0; nd < 2; nd++) {
#pragma unroll
            for (int r = 0; r < 4; r++) {
                int row = s * SSZ + wq * 32 + mt * 16 + (lane >> 4) * 4 + r;
                int col = h * HDIM + nd * 16 + rr;
                ao[(size_t)row * DM + col] = f2bf(O[mt][nd][r] / rs[mt][r]);
            }
        }
    }
}

// ======================== LayerNorm helpers =======================
__device__ inline float4 ln4(float4 t, int lane, const float* __restrict__ g,
                             const float* __restrict__ b) {
    float s = t.x + t.y + t.z + t.w;
    float s2 = t.x * t.x + t.y * t.y + t.z * t.z + t.w * t.w;
#pragma unroll
    for (int off = 32; off; off >>= 1) {
        s += __shfl_xor(s, off);
        s2 += __shfl_xor(s2, off);
    }
    float mean = s * (1.0f / 256.0f);
    float var = fmaf(-mean, mean, s2 * (1.0f / 256.0f));
    float rs = rsqrtf(var + 1e-5f);
    float4 g4 = ((const float4*)g)[lane];
    float4 b4 = ((const float4*)b)[lane];
    float4 o;
    o.x = fmaf((t.x - mean) * rs, g4.x, b4.x);
    o.y = fmaf((t.y - mean) * rs, g4.y, b4.y);
    o.z = fmaf((t.z - mean) * rs, g4.z, b4.z);
    o.w = fmaf((t.w - mean) * rs, g4.w, b4.w);
    return o;
}

// x[inds[j]] = LN(prev[inds[j]] + a[j]); a is bf16; dual write f32 + bf16
__global__ __launch_bounds__(256)
void scatter_ln_kernel(const unsigned short* __restrict__ a, const int* __restrict__ inds,
                       const float* __restrict__ prev,
                       const float* __restrict__ g, const float* __restrict__ b,
                       float* __restrict__ x, unsigned short* __restrict__ x_bf) {
    int j = blockIdx.x * 4 + (threadIdx.x >> 6);
    int lane = threadIdx.x & 63;
    int v = inds[j];
    ushort4 av = ((const ushort4*)(a + (size_t)j * DM))[lane];
    float4 pv = ((const float4*)(prev + (size_t)v * DM))[lane];
    float4 t = make_float4(bf2f(av.x) + pv.x, bf2f(av.y) + pv.y,
                           bf2f(av.z) + pv.z, bf2f(av.w) + pv.w);
    float4 o = ln4(t, lane, g, b);
    ((float4*)(x + (size_t)v * DM))[lane] = o;
    ushort4 ob;
    ob.x = f2bf(o.x); ob.y = f2bf(o.y); ob.z = f2bf(o.z); ob.w = f2bf(o.w);
    ((ushort4*)(x_bf + (size_t)v * DM))[lane] = ob;
}

// out[v] = LN( LN(x[v]+y[v], g2,b2) + prev[v], gl,bl )
__global__ __launch_bounds__(256)
void final_ln_kernel(const float* __restrict__ x, const float* __restrict__ y,
                     const float* __restrict__ prev,
                     const float* __restrict__ g2, const float* __restrict__ b2,
                     const float* __restrict__ gl, const float* __restrict__ bl,
                     float* __restrict__ out) {
    int v = blockIdx.x * 4 + (threadIdx.x >> 6);
    int lane = threadIdx.x & 63;
    size_t base = (size_t)v * DM;
    float4 xv = ((const float4*)(x + base))[lane];
    float4 yv = ((const float4*)(y + base))[lane];
    float4 t = make_float4(xv.x + yv.x, xv.y + yv.y, xv.z + yv.z, xv.w + yv.w);
    float4 t2 = ln4(t, lane, g2, b2);
    float4 pv = ((const float4*)(prev + base))[lane];
    float4 u = make_float4(t2.x + pv.x, t2.y + pv.y, t2.z + pv.z, t2.w + pv.w);
    float4 o = ln4(u, lane, gl, bl);
    ((float4*)(out + base))[lane] = o;
}

// ============================= launch =============================
extern "C" void kernel_launch(void* const* d_in, const int* in_sizes, int n_in,
                              void* d_out, int out_size, void* d_ws, size_t ws_size,
                              hipStream_t stream) {
    const float* src       = (const float*)d_in[0];
    const float* pos_embed = (const float*)d_in[1];
    const int*   inds_all  = (const int*)d_in[2];
    const unsigned char* masks_all = (const unsigned char*)d_in[3];
    const float* w_qkv = (const float*)d_in[4];
    const float* b_qkv = (const float*)d_in[5];
    const float* w_out = (const float*)d_in[6];
    const float* b_out = (const float*)d_in[7];
    const float* w_ff1 = (const float*)d_in[8];
    const float* b_ff1 = (const float*)d_in[9];
    const float* w_ff2 = (const float*)d_in[10];
    const float* b_ff2 = (const float*)d_in[11];
    const float* g_n1 = (const float*)d_in[12];
    const float* b_n1 = (const float*)d_in[13];
    const float* g_n2 = (const float*)d_in[14];
    const float* b_n2 = (const float*)d_in[15];
    const float* g_ln = (const float*)d_in[16];
    const float* b_ln = (const float*)d_in[17];
    float* out = (float*)d_out;

    const size_t NVF = (size_t)NVOX * DM;  // 16,777,216
    unsigned short* A = (unsigned short*)d_ws;   // NVF u16: qk_bf -> ao_bf
    unsigned short* B = A + NVF;                 // NVF u16: feat_bf -> x_bf
    unsigned short* C = B + NVF;                 // 2*NVF u16: [Q|K] -> a_bf -> y(f32)
    unsigned short* D = C + 2 * NVF;             // NVF u16: V bf16
    float* F = (float*)(D + NVF);                // NVF f32: x
    unsigned short* wts = (unsigned short*)(F + NVF);
    const size_t SZ_QKV = (size_t)2 * 3 * DM * DM;
    const size_t SZ_WO  = (size_t)2 * DM * DM;
    const size_t SZ_FF1 = (size_t)2 * DFFN * DM;
    const size_t SZ_FF2 = (size_t)2 * DM * DFFN;
    unsigned short* wqkv_bf = wts;
    unsigned short* wo_bf   = wqkv_bf + SZ_QKV;
    unsigned short* wff1_bf = wo_bf + SZ_WO;
    unsigned short* wff2_bf = wff1_bf + SZ_FF1;
    unsigned short* hbuf    = wff2_bf + SZ_FF2;

    size_t used_bytes = (char*)hbuf - (char*)d_ws;
    long long avail = (long long)ws_size - (long long)used_bytes;
    long long crows = avail / (DFFN * 2);
    if (crows > NVOX) crows = NVOX;
    crows &= ~127LL;
    int chunk = (crows < 128) ? 128 : (int)crows;

    cvt_bf16_kernel<<<512, 256, 0, stream>>>(w_qkv, wqkv_bf, (int)SZ_QKV);
    cvt_bf16_kernel<<<256, 256, 0, stream>>>(w_out, wo_bf, (int)SZ_WO);
    cvt_bf16_kernel<<<1024, 256, 0, stream>>>(w_ff1, wff1_bf, (int)SZ_FF1);
    cvt_bf16_kernel<<<1024, 256, 0, stream>>>(w_ff2, wff2_bf, (int)SZ_FF2);

    for (int i = 0; i < 2; i++) {
        const float* prev = (i == 0) ? src : out;
        const int* inds = inds_all + (size_t)i * 2 * SNUM * SSZ;
        const unsigned char* mask = masks_all + (size_t)i * 2 * SNUM * SSZ;
        const float* pos  = pos_embed + (size_t)i * NVF;
        const unsigned short* wqkv = wqkv_bf + (size_t)i * 3 * DM * DM;
        const unsigned short* wo   = wo_bf + (size_t)i * DM * DM;
        const unsigned short* wff1 = wff1_bf + (size_t)i * DFFN * DM;
        const unsigned short* wff2 = wff2_bf + (size_t)i * DM * DFFN;
        const float* bqkv = b_qkv + (size_t)i * 3 * DM;
        const float* bo   = b_out + (size_t)i * DM;
        const float* bff1 = b_ff1 + (size_t)i * DFFN;
        const float* bff2 = b_ff2 + (size_t)i * DM;

        gather_kernel<<<NVOX / 4, 256, 0, stream>>>(prev, pos, inds, A, B);

        gemm_mfma<false, true><<<dim3(NVOX / 128, 512 / 128), 256, 0, stream>>>(
            A, wqkv, bqkv, C, NVOX, 512, DM);
        gemm_mfma<false, true><<<dim3(NVOX / 128, DM / 128), 256, 0, stream>>>(
            B, wqkv + (size_t)512 * DM, bqkv + 512, D, NVOX, DM, DM);

        attn_mfma_kernel<<<dim3(SNUM, NH), 256, 0, stream>>>(C, D, mask, A);

        gemm_mfma<false, true><<<dim3(NVOX / 128, DM / 128), 256, 0, stream>>>(
            A, wo, bo, C, NVOX, DM, DM);

        scatter_ln_kernel<<<NVOX / 4, 256, 0, stream>>>(
            C, inds, prev, g_n1 + i * DM, b_n1 + i * DM, F, B);

        float* y = (float*)C;
        for (int r0 = 0; r0 < NVOX; r0 += chunk) {
            int rows = (NVOX - r0 < chunk) ? (NVOX - r0) : chunk;
            gemm_mfma<true, true><<<dim3(rows / 128, DFFN / 128), 256, 0, stream>>>(
                B + (size_t)r0 * DM, wff1, bff1, hbuf, rows, DFFN, DM);
            gemm_mfma<false, false><<<dim3(rows / 128, DM / 128), 256, 0, stream>>>(
                hbuf, wff2, bff2, y + (size_t)r0 * DM, rows, DM, DFFN);
        }

        final_ln_kernel<<<NVOX / 4, 256, 0, stream>>>(
            F, y, prev, g_n2 + i * DM, b_n2 + i * DM,
            g_ln + i * DM, b_ln + i * DM, out);
    }
}

// Round 6
// 1187.670 us; speedup vs baseline: 1.1207x; 1.1207x over previous
//
#include <hip/hip_runtime.h>
#include <math.h>

#define NVOX 65536
#define DM 256
#define NH 8
#define HDIM 32
#define DFFN 2048
#define SSZ 128
#define SNUM 512

#define AS1 __attribute__((address_space(1)))
#define AS3 __attribute__((address_space(3)))

typedef __attribute__((ext_vector_type(8))) __bf16 bf16x8;
typedef __attribute__((ext_vector_type(8))) unsigned short u16x8;
typedef __attribute__((ext_vector_type(4))) float f32x4;

__device__ __forceinline__ unsigned short f2bf(float f) {
    unsigned int u = __float_as_uint(f);
    u += 0x7fffu + ((u >> 16) & 1u);
    return (unsigned short)(u >> 16);
}
__device__ __forceinline__ float bf2f(unsigned short u) {
    return __uint_as_float(((unsigned int)u) << 16);
}

// ===================== weight fp32 -> bf16 ========================
__global__ __launch_bounds__(256)
void cvt_bf16_kernel(const float* __restrict__ in, unsigned short* __restrict__ out, int n) {
    int i = blockIdx.x * 256 + threadIdx.x;
    int stride = gridDim.x * 256;
    for (; i < n; i += stride) out[i] = f2bf(in[i]);
}

// ============================= gather =============================
__global__ __launch_bounds__(256)
void gather_kernel(const float* __restrict__ src, const float* __restrict__ pos,
                   const int* __restrict__ inds,
                   unsigned short* __restrict__ qk, unsigned short* __restrict__ feat) {
    int j = blockIdx.x * 4 + (threadIdx.x >> 6);
    int lane = threadIdx.x & 63;
    int v = inds[j];
    float4 a = ((const float4*)(src + (size_t)v * DM))[lane];
    float4 p = ((const float4*)(pos + (size_t)v * DM))[lane];
    ushort4 qo, fo;
    qo.x = f2bf(a.x + p.x); qo.y = f2bf(a.y + p.y);
    qo.z = f2bf(a.z + p.z); qo.w = f2bf(a.w + p.w);
    fo.x = f2bf(a.x); fo.y = f2bf(a.y); fo.z = f2bf(a.z); fo.w = f2bf(a.w);
    ((ushort4*)(qk   + (size_t)j * DM))[lane] = qo;
    ((ushort4*)(feat + (size_t)j * DM))[lane] = fo;
}

// ==================== 256x256 pipelined MFMA GEMM =================
// C[M,N] = A[M,K](bf16) @ W[N,K](bf16)^T + bias[N](f32); opt ReLU; out f32/bf16.
// BM=BN=256, BK=32, 512 thr (8 waves, wm=wave>>2 (2) x wn=wave&3 (4)),
// per-wave out 128x64 (acc[8][4]). Fragment-order LDS (lane-linear b128,
// conflict-free). Double-buffered, COUNTED vmcnt(4): next tile's loads stay
// in flight across the barrier (T3+T4); raw s_barrier (no compiler drain).
#define VMCNT4 asm volatile("s_waitcnt vmcnt(4)" ::: "memory")
#define VMCNT0 asm volatile("s_waitcnt vmcnt(0)" ::: "memory")

template<bool RELU, bool OBF16>
__global__ __launch_bounds__(512)
void gemm_mfma256(const unsigned short* __restrict__ A, const unsigned short* __restrict__ W,
                  const float* __restrict__ bias, void* __restrict__ Cout,
                  int M, int N, int K) {
    // LDS: As[2][16 subtiles][512 u16] = 32KB, Bs same at +32KB (64KB total);
    // epilogue f32 strip 64x264 (67.6KB) aliased over everything afterwards.
    __shared__ alignas(16) char smem[69632];
    unsigned short* As = (unsigned short*)smem;
    unsigned short* Bs = (unsigned short*)(smem + 32768);
    float* ebuf = (float*)smem;
    const int ES = 264;  // 264 % 32 = 8 -> staggered banks across rows

    int tid = threadIdx.x;
    int wave = tid >> 6, lane = tid & 63;
    int wm = wave >> 2;          // 0..1 -> rows wm*128..+128
    int wn = wave & 3;           // 0..3 -> cols wn*64..+64
    int mBase = blockIdx.x * 256, nBase = blockIdx.y * 256;

    int rr = lane & 15;          // fragment row
    int kq = (lane >> 4) * 8;    // fragment k-offset
    int rbase = (lane >> 4) * 4;

    f32x4 acc[8][4];
    const f32x4 zero = {0.f, 0.f, 0.f, 0.f};
#pragma unroll
    for (int m = 0; m < 8; m++)
#pragma unroll
        for (int n = 0; n < 4; n++) acc[m][n] = zero;

    // per-lane global sources: wave stages A-subtiles {2w,2w+1}, B same.
    const unsigned short* gA0 = A + (size_t)(mBase + (wave * 2 + 0) * 16 + rr) * K + kq;
    const unsigned short* gA1 = A + (size_t)(mBase + (wave * 2 + 1) * 16 + rr) * K + kq;
    const unsigned short* gB0 = W + (size_t)(nBase + (wave * 2 + 0) * 16 + rr) * K + kq;
    const unsigned short* gB1 = W + (size_t)(nBase + (wave * 2 + 1) * 16 + rr) * K + kq;

    auto stage = [&](int b, int kt) {
        int ko = kt * 32;
        __builtin_amdgcn_global_load_lds((const AS1 void*)(gA0 + ko),
            (AS3 void*)(As + b * 8192 + (wave * 2 + 0) * 512), 16, 0, 0);
        __builtin_amdgcn_global_load_lds((const AS1 void*)(gA1 + ko),
            (AS3 void*)(As + b * 8192 + (wave * 2 + 1) * 512), 16, 0, 0);
        __builtin_amdgcn_global_load_lds((const AS1 void*)(gB0 + ko),
            (AS3 void*)(Bs + b * 8192 + (wave * 2 + 0) * 512), 16, 0, 0);
        __builtin_amdgcn_global_load_lds((const AS1 void*)(gB1 + ko),
            (AS3 void*)(Bs + b * 8192 + (wave * 2 + 1) * 512), 16, 0, 0);
    };

    int nt = K >> 5;
    stage(0, 0);                         // prologue: 4 loads outstanding

    for (int t = 0; t < nt; ++t) {
        int p = t & 1;
        if (t + 1 < nt) {
            stage(p ^ 1, t + 1);         // 4 more in flight (8 total)
            VMCNT4;                      // wait ONLY tile t's 4; t+1 stays airborne
        } else {
            VMCNT0;
        }
        __builtin_amdgcn_s_barrier();    // all waves' tile-t loads landed
        __builtin_amdgcn_sched_barrier(0);

        bf16x8 af[8], bf[4];
#pragma unroll
        for (int m = 0; m < 8; m++)
            af[m] = *(const bf16x8*)(As + p * 8192 + (wm * 8 + m) * 512 + lane * 8);
#pragma unroll
        for (int n = 0; n < 4; n++)
            bf[n] = *(const bf16x8*)(Bs + p * 8192 + (wn * 4 + n) * 512 + lane * 8);
#pragma unroll
        for (int m = 0; m < 8; m++)
#pragma unroll
            for (int n = 0; n < 4; n++)
                acc[m][n] = __builtin_amdgcn_mfma_f32_16x16x32_bf16(af[m], bf[n], acc[m][n], 0, 0, 0);

        __builtin_amdgcn_sched_barrier(0);
        __builtin_amdgcn_s_barrier();    // all waves done reading buf p
    }

    // ---- epilogue: 4 passes of 64 rows via LDS, full-line stores ----
    float bn[4];
#pragma unroll
    for (int n = 0; n < 4; n++)
        bn[n] = bias[nBase + wn * 64 + n * 16 + rr];

    int erow = tid >> 3;              // 0..63
    int ec0  = (tid & 7) * 32;        // 0..224
#pragma unroll
    for (int pass = 0; pass < 4; ++pass) {
        __syncthreads();
        if (wm == (pass >> 1)) {
#pragma unroll
            for (int mm = 0; mm < 4; ++mm) {
                int m = (pass & 1) * 4 + mm;
#pragma unroll
                for (int n = 0; n < 4; ++n) {
                    int lcol = wn * 64 + n * 16 + rr;
#pragma unroll
                    for (int r = 0; r < 4; ++r) {
                        float v = acc[m][n][r] + bn[n];
                        if (RELU) v = fmaxf(v, 0.f);
                        ebuf[(mm * 16 + rbase + r) * ES + lcol] = v;
                    }
                }
            }
        }
        __syncthreads();
        int grow = mBase + pass * 64 + erow;
        if (OBF16) {
            unsigned short* dst = (unsigned short*)Cout + (size_t)grow * N + nBase + ec0;
#pragma unroll
            for (int g = 0; g < 4; ++g) {
                u16x8 o;
#pragma unroll
                for (int j = 0; j < 8; ++j)
                    o[j] = f2bf(ebuf[erow * ES + ec0 + g * 8 + j]);
                *(u16x8*)(dst + g * 8) = o;
            }
        } else {
            float* dst = (float*)Cout + (size_t)grow * N + nBase + ec0;
#pragma unroll
            for (int g = 0; g < 8; ++g)
                *(float4*)(dst + g * 4) = *(float4*)(ebuf + erow * ES + ec0 + g * 4);
        }
    }
}

// ======================= MFMA attention ===========================
__global__ __launch_bounds__(256)
void attn_mfma_kernel(const unsigned short* __restrict__ QK,
                      const unsigned short* __restrict__ V,
                      const unsigned char* __restrict__ mask,
                      unsigned short* __restrict__ ao) {
    int s = blockIdx.x, h = blockIdx.y;
    int tid = threadIdx.x;
    int wq = tid >> 6;
    int lane = tid & 63;

    __shared__ alignas(16) unsigned short Ks[128 * 40];
    __shared__ alignas(16) unsigned short Vt[32 * 136];
    __shared__ alignas(16) unsigned short Plds[4 * 4096];
    __shared__ unsigned char msk[SSZ];

#pragma unroll
    for (int it = 0; it < 2; it++) {
        int idx = tid + it * 256;
        int key = idx >> 2, dimoff = (idx & 3) * 8;
        bf16x8 kv = *(const bf16x8*)(QK + (size_t)(s * SSZ + key) * 512 + 256 + h * HDIM + dimoff);
        *(bf16x8*)(Ks + key * 40 + dimoff) = kv;
        u16x8 vv = *(const u16x8*)(V + (size_t)(s * SSZ + key) * DM + h * HDIM + dimoff);
#pragma unroll
        for (int j = 0; j < 8; j++) Vt[(dimoff + j) * 136 + key] = vv[j];
    }
    if (tid < SSZ) msk[tid] = mask[s * SSZ + tid];
    __syncthreads();

    int rr = lane & 15;
    int kq = (lane >> 4) * 8;
    const f32x4 zero = {0.f, 0.f, 0.f, 0.f};

    bf16x8 qa[2];
#pragma unroll
    for (int mt = 0; mt < 2; mt++)
        qa[mt] = *(const bf16x8*)(QK + (size_t)(s * SSZ + wq * 32 + mt * 16 + rr) * 512 + h * HDIM + kq);

    f32x4 S[2][8];
#pragma unroll
    for (int nt = 0; nt < 8; nt++) {
        bf16x8 kb = *(const bf16x8*)(Ks + (nt * 16 + rr) * 40 + kq);
#pragma unroll
        for (int mt = 0; mt < 2; mt++)
            S[mt][nt] = __builtin_amdgcn_mfma_f32_16x16x32_bf16(qa[mt], kb, zero, 0, 0, 0);
    }

    const float SCALE = 0.17677669529663687f;
    f32x4 rm[2];
#pragma unroll
    for (int mt = 0; mt < 2; mt++) { rm[mt].x = rm[mt].y = rm[mt].z = rm[mt].w = -1e30f; }
#pragma unroll
    for (int nt = 0; nt < 8; nt++) {
        bool mv = msk[nt * 16 + rr] != 0;
#pragma unroll
        for (int mt = 0; mt < 2; mt++) {
#pragma unroll
            for (int r = 0; r < 4; r++) {
                float v = mv ? -1e30f : S[mt][nt][r] * SCALE;
                S[mt][nt][r] = v;
                rm[mt][r] = fmaxf(rm[mt][r], v);
            }
        }
    }
#pragma unroll
    for (int off = 1; off < 16; off <<= 1) {
#pragma unroll
        for (int mt = 0; mt < 2; mt++)
#pragma unroll
            for (int r = 0; r < 4; r++)
                rm[mt][r] = fmaxf(rm[mt][r], __shfl_xor(rm[mt][r], off));
    }

    f32x4 rs[2];
#pragma unroll
    for (int mt = 0; mt < 2; mt++) { rs[mt] = zero; }
#pragma unroll
    for (int nt = 0; nt < 8; nt++)
#pragma unroll
        for (int mt = 0; mt < 2; mt++)
#pragma unroll
            for (int r = 0; r < 4; r++) {
                float p = __expf(S[mt][nt][r] - rm[mt][r]);
                S[mt][nt][r] = p;
                rs[mt][r] += p;
            }
#pragma unroll
    for (int off = 1; off < 16; off <<= 1) {
#pragma unroll
        for (int mt = 0; mt < 2; mt++)
#pragma unroll
            for (int r = 0; r < 4; r++)
                rs[mt][r] += __shfl_xor(rs[mt][r], off);
    }

    char* Pbase = (char*)Plds + wq * 8192;
#pragma unroll
    for (int nt = 0; nt < 8; nt++)
#pragma unroll
        for (int mt = 0; mt < 2; mt++)
#pragma unroll
            for (int r = 0; r < 4; r++) {
                int prow = mt * 16 + (lane >> 4) * 4 + r;
                int col  = nt * 16 + rr;
                unsigned addr = (unsigned)(prow * 256 + col * 2) ^ ((prow & 7) << 4);
                *(unsigned short*)(Pbase + addr) = f2bf(S[mt][nt][r]);
            }
    __syncthreads();

    f32x4 O[2][2];
#pragma unroll
    for (int mt = 0; mt < 2; mt++)
#pragma unroll
        for (int nd = 0; nd < 2; nd++) O[mt][nd] = zero;
#pragma unroll
    for (int kc = 0; kc < 4; kc++) {
        bf16x8 pa[2];
#pragma unroll
        for (int mt = 0; mt < 2; mt++) {
            int prow = mt * 16 + rr;
            unsigned addr = (unsigned)(prow * 256 + (kc * 32 + kq) * 2) ^ ((prow & 7) << 4);
            pa[mt] = *(const bf16x8*)(Pbase + addr);
        }
#pragma unroll
        for (int nd = 0; nd < 2; nd++) {
            bf16x8 vb = *(const bf16x8*)(Vt + (nd * 16 + rr) * 136 + kc * 32 + kq);
#pragma unroll
            for (int mt = 0; mt < 2; mt++)
                O[mt][nd] = __builtin_amdgcn_mfma_f32_16x16x32_bf16(pa[mt], vb, O[mt][nd], 0, 0, 0);
        }
    }

#pragma unroll
    for (int mt = 0; mt < 2; mt++) {
#pragma unroll
        for (int nd = 0; nd < 2; nd++) {
#pragma unroll
            for (int r = 0; r < 4; r++) {
                int row = s * SSZ + wq * 32 + mt * 16 + (lane >> 4) * 4 + r;
                int col = h * HDIM + nd * 16 + rr;
                ao[(size_t)row * DM + col] = f2bf(O[mt][nd][r] / rs[mt][r]);
            }
        }
    }
}

// ======================== LayerNorm helpers =======================
__device__ inline float4 ln4(float4 t, int lane, const float* __restrict__ g,
                             const float* __restrict__ b) {
    float s = t.x + t.y + t.z + t.w;
    float s2 = t.x * t.x + t.y * t.y + t.z * t.z + t.w * t.w;
#pragma unroll
    for (int off = 32; off; off >>= 1) {
        s += __shfl_xor(s, off);
        s2 += __shfl_xor(s2, off);
    }
    float mean = s * (1.0f / 256.0f);
    float var = fmaf(-mean, mean, s2 * (1.0f / 256.0f));
    float rs = rsqrtf(var + 1e-5f);
    float4 g4 = ((const float4*)g)[lane];
    float4 b4 = ((const float4*)b)[lane];
    float4 o;
    o.x = fmaf((t.x - mean) * rs, g4.x, b4.x);
    o.y = fmaf((t.y - mean) * rs, g4.y, b4.y);
    o.z = fmaf((t.z - mean) * rs, g4.z, b4.z);
    o.w = fmaf((t.w - mean) * rs, g4.w, b4.w);
    return o;
}

__global__ __launch_bounds__(256)
void scatter_ln_kernel(const unsigned short* __restrict__ a, const int* __restrict__ inds,
                       const float* __restrict__ prev,
                       const float* __restrict__ g, const float* __restrict__ b,
                       float* __restrict__ x, unsigned short* __restrict__ x_bf) {
    int j = blockIdx.x * 4 + (threadIdx.x >> 6);
    int lane = threadIdx.x & 63;
    int v = inds[j];
    ushort4 av = ((const ushort4*)(a + (size_t)j * DM))[lane];
    float4 pv = ((const float4*)(prev + (size_t)v * DM))[lane];
    float4 t = make_float4(bf2f(av.x) + pv.x, bf2f(av.y) + pv.y,
                           bf2f(av.z) + pv.z, bf2f(av.w) + pv.w);
    float4 o = ln4(t, lane, g, b);
    ((float4*)(x + (size_t)v * DM))[lane] = o;
    ushort4 ob;
    ob.x = f2bf(o.x); ob.y = f2bf(o.y); ob.z = f2bf(o.z); ob.w = f2bf(o.w);
    ((ushort4*)(x_bf + (size_t)v * DM))[lane] = ob;
}

__global__ __launch_bounds__(256)
void final_ln_kernel(const float* __restrict__ x, const float* __restrict__ y,
                     const float* __restrict__ prev,
                     const float* __restrict__ g2, const float* __restrict__ b2,
                     const float* __restrict__ gl, const float* __restrict__ bl,
                     float* __restrict__ out) {
    int v = blockIdx.x * 4 + (threadIdx.x >> 6);
    int lane = threadIdx.x & 63;
    size_t base = (size_t)v * DM;
    float4 xv = ((const float4*)(x + base))[lane];
    float4 yv = ((const float4*)(y + base))[lane];
    float4 t = make_float4(xv.x + yv.x, xv.y + yv.y, xv.z + yv.z, xv.w + yv.w);
    float4 t2 = ln4(t, lane, g2, b2);
    float4 pv = ((const float4*)(prev + base))[lane];
    float4 u = make_float4(t2.x + pv.x, t2.y + pv.y, t2.z + pv.z, t2.w + pv.w);
    float4 o = ln4(u, lane, gl, bl);
    ((float4*)(out + base))[lane] = o;
}

// ============================= launch =============================
extern "C" void kernel_launch(void* const* d_in, const int* in_sizes, int n_in,
                              void* d_out, int out_size, void* d_ws, size_t ws_size,
                              hipStream_t stream) {
    const float* src       = (const float*)d_in[0];
    const float* pos_embed = (const float*)d_in[1];
    const int*   inds_all  = (const int*)d_in[2];
    const unsigned char* masks_all = (const unsigned char*)d_in[3];
    const float* w_qkv = (const float*)d_in[4];
    const float* b_qkv = (const float*)d_in[5];
    const float* w_out = (const float*)d_in[6];
    const float* b_out = (const float*)d_in[7];
    const float* w_ff1 = (const float*)d_in[8];
    const float* b_ff1 = (const float*)d_in[9];
    const float* w_ff2 = (const float*)d_in[10];
    const float* b_ff2 = (const float*)d_in[11];
    const float* g_n1 = (const float*)d_in[12];
    const float* b_n1 = (const float*)d_in[13];
    const float* g_n2 = (const float*)d_in[14];
    const float* b_n2 = (const float*)d_in[15];
    const float* g_ln = (const float*)d_in[16];
    const float* b_ln = (const float*)d_in[17];
    float* out = (float*)d_out;

    const size_t NVF = (size_t)NVOX * DM;  // 16,777,216
    unsigned short* A = (unsigned short*)d_ws;   // NVF u16: qk_bf -> ao_bf
    unsigned short* B = A + NVF;                 // NVF u16: feat_bf -> x_bf
    unsigned short* C = B + NVF;                 // 2*NVF u16: [Q|K] -> a_bf -> y(f32)
    unsigned short* D = C + 2 * NVF;             // NVF u16: V bf16
    float* F = (float*)(D + NVF);                // NVF f32: x
    unsigned short* wts = (unsigned short*)(F + NVF);
    const size_t SZ_QKV = (size_t)2 * 3 * DM * DM;
    const size_t SZ_WO  = (size_t)2 * DM * DM;
    const size_t SZ_FF1 = (size_t)2 * DFFN * DM;
    const size_t SZ_FF2 = (size_t)2 * DM * DFFN;
    unsigned short* wqkv_bf = wts;
    unsigned short* wo_bf   = wqkv_bf + SZ_QKV;
    unsigned short* wff1_bf = wo_bf + SZ_WO;
    unsigned short* wff2_bf = wff1_bf + SZ_FF1;
    unsigned short* hbuf    = wff2_bf + SZ_FF2;

    size_t used_bytes = (char*)hbuf - (char*)d_ws;
    long long avail = (long long)ws_size - (long long)used_bytes;
    long long crows = avail / (DFFN * 2);
    if (crows > NVOX) crows = NVOX;
    crows &= ~255LL;                       // gemm256 needs row multiples of 256
    int chunk = (crows < 256) ? 256 : (int)crows;

    cvt_bf16_kernel<<<512, 256, 0, stream>>>(w_qkv, wqkv_bf, (int)SZ_QKV);
    cvt_bf16_kernel<<<256, 256, 0, stream>>>(w_out, wo_bf, (int)SZ_WO);
    cvt_bf16_kernel<<<1024, 256, 0, stream>>>(w_ff1, wff1_bf, (int)SZ_FF1);
    cvt_bf16_kernel<<<1024, 256, 0, stream>>>(w_ff2, wff2_bf, (int)SZ_FF2);

    for (int i = 0; i < 2; i++) {
        const float* prev = (i == 0) ? src : out;
        const int* inds = inds_all + (size_t)i * 2 * SNUM * SSZ;
        const unsigned char* mask = masks_all + (size_t)i * 2 * SNUM * SSZ;
        const float* pos  = pos_embed + (size_t)i * NVF;
        const unsigned short* wqkv = wqkv_bf + (size_t)i * 3 * DM * DM;
        const unsigned short* wo   = wo_bf + (size_t)i * DM * DM;
        const unsigned short* wff1 = wff1_bf + (size_t)i * DFFN * DM;
        const unsigned short* wff2 = wff2_bf + (size_t)i * DM * DFFN;
        const float* bqkv = b_qkv + (size_t)i * 3 * DM;
        const float* bo   = b_out + (size_t)i * DM;
        const float* bff1 = b_ff1 + (size_t)i * DFFN;
        const float* bff2 = b_ff2 + (size_t)i * DM;

        gather_kernel<<<NVOX / 4, 256, 0, stream>>>(prev, pos, inds, A, B);

        // [Q|K] = qk @ [Wq;Wk]^T -> C (bf16, NVOX x 512)
        gemm_mfma256<false, true><<<dim3(NVOX / 256, 512 / 256), 512, 0, stream>>>(
            A, wqkv, bqkv, C, NVOX, 512, DM);
        // V = feat @ Wv^T -> D (bf16)
        gemm_mfma256<false, true><<<dim3(NVOX / 256, 1), 512, 0, stream>>>(
            B, wqkv + (size_t)512 * DM, bqkv + 512, D, NVOX, DM, DM);

        attn_mfma_kernel<<<dim3(SNUM, NH), 256, 0, stream>>>(C, D, mask, A);

        // a = ao @ Wo^T + bo -> C (bf16)
        gemm_mfma256<false, true><<<dim3(NVOX / 256, 1), 512, 0, stream>>>(
            A, wo, bo, C, NVOX, DM, DM);

        scatter_ln_kernel<<<NVOX / 4, 256, 0, stream>>>(
            C, inds, prev, g_n1 + i * DM, b_n1 + i * DM, F, B);

        float* y = (float*)C;
        for (int r0 = 0; r0 < NVOX; r0 += chunk) {
            int rows = (NVOX - r0 < chunk) ? (NVOX - r0) : chunk;
            gemm_mfma256<true, true><<<dim3(rows / 256, DFFN / 256), 512, 0, stream>>>(
                B + (size_t)r0 * DM, wff1, bff1, hbuf, rows, DFFN, DM);
            gemm_mfma256<false, false><<<dim3(rows / 256, 1), 512, 0, stream>>>(
                hbuf, wff2, bff2, y + (size_t)r0 * DM, rows, DM, DFFN);
        }

        final_ln_kernel<<<NVOX / 4, 256, 0, stream>>>(
            F, y, prev, g_n2 + i * DM, b_n2 + i * DM,
            g_ln + i * DM, b_ln + i * DM, out);
    }
}

// Round 7
// 1173.088 us; speedup vs baseline: 1.1346x; 1.0124x over previous
//
#include <hip/hip_runtime.h>
#include <math.h>

#define NVOX 65536
#define DM 256
#define NH 8
#define HDIM 32
#define DFFN 2048
#define SSZ 128
#define SNUM 512

#define AS1 __attribute__((address_space(1)))
#define AS3 __attribute__((address_space(3)))

typedef __attribute__((ext_vector_type(8))) __bf16 bf16x8;
typedef __attribute__((ext_vector_type(8))) unsigned short u16x8;
typedef __attribute__((ext_vector_type(4))) float f32x4;

__device__ __forceinline__ unsigned short f2bf(float f) {
    unsigned int u = __float_as_uint(f);
    u += 0x7fffu + ((u >> 16) & 1u);
    return (unsigned short)(u >> 16);
}
__device__ __forceinline__ float bf2f(unsigned short u) {
    return __uint_as_float(((unsigned int)u) << 16);
}

// ===================== weight fp32 -> bf16 ========================
__global__ __launch_bounds__(256)
void cvt_bf16_kernel(const float* __restrict__ in, unsigned short* __restrict__ out, int n) {
    int i = blockIdx.x * 256 + threadIdx.x;
    int stride = gridDim.x * 256;
    for (; i < n; i += stride) out[i] = f2bf(in[i]);
}

// ============================= gather =============================
__global__ __launch_bounds__(256)
void gather_kernel(const float* __restrict__ src, const float* __restrict__ pos,
                   const int* __restrict__ inds,
                   unsigned short* __restrict__ qk, unsigned short* __restrict__ feat) {
    int j = blockIdx.x * 4 + (threadIdx.x >> 6);
    int lane = threadIdx.x & 63;
    int v = inds[j];
    float4 a = ((const float4*)(src + (size_t)v * DM))[lane];
    float4 p = ((const float4*)(pos + (size_t)v * DM))[lane];
    ushort4 qo, fo;
    qo.x = f2bf(a.x + p.x); qo.y = f2bf(a.y + p.y);
    qo.z = f2bf(a.z + p.z); qo.w = f2bf(a.w + p.w);
    fo.x = f2bf(a.x); fo.y = f2bf(a.y); fo.z = f2bf(a.z); fo.w = f2bf(a.w);
    ((ushort4*)(qk   + (size_t)j * DM))[lane] = qo;
    ((ushort4*)(feat + (size_t)j * DM))[lane] = fo;
}

// ==================== 256x256 pipelined MFMA GEMM =================
// C = A@W^T + bias, 256x256 tile, BK=32, 8 waves, counted vmcnt(4),
// fragment-order LDS (conflict-free). Fused epilogues:
//  EPI 0: bf16 out (opt ReLU)        EPI 1: f32 out
//  EPI 2: x = LN(ebuf + res1[inds[row]]) -> Cout f32 + out2 bf16 (scatter)
//  EPI 3: out = LN( LN(ebuf + res2[row], g1,b1) + res1[row], g2,b2 ) f32
// EPI 2/3 require N == 256 (full row per tile).
#define VMCNT4 asm volatile("s_waitcnt vmcnt(4)" ::: "memory")
#define VMCNT0 asm volatile("s_waitcnt vmcnt(0)" ::: "memory")

template<int EPI, bool RELU>
__global__ __launch_bounds__(512)
void gemm_mfma256(const unsigned short* __restrict__ A, const unsigned short* __restrict__ W,
                  const float* __restrict__ bias, void* __restrict__ Cout,
                  int M, int N, int K,
                  const int* __restrict__ inds,
                  const float* __restrict__ res1, const float* __restrict__ res2,
                  const float* __restrict__ g1, const float* __restrict__ b1,
                  const float* __restrict__ g2, const float* __restrict__ b2,
                  unsigned short* __restrict__ out2) {
    __shared__ alignas(16) char smem[69632];
    unsigned short* As = (unsigned short*)smem;
    unsigned short* Bs = (unsigned short*)(smem + 32768);
    float* ebuf = (float*)smem;
    const int ES = 264;

    int tid = threadIdx.x;
    int wave = tid >> 6, lane = tid & 63;
    int wm = wave >> 2;
    int wn = wave & 3;

    // XCD-aware swizzle (T1), N-major decode: per-XCD contiguous range
    // walks the weight blocks fast -> A-tile reused, W L2-resident.
    unsigned lin = blockIdx.x + blockIdx.y * gridDim.x;
    unsigned nwg = gridDim.x * gridDim.y;
    unsigned swz = lin;
    if ((nwg & 7u) == 0u) { unsigned cpx = nwg >> 3; swz = (lin & 7u) * cpx + (lin >> 3); }
    int bx = (int)(swz / gridDim.y);
    int by = (int)(swz % gridDim.y);
    int mBase = bx * 256, nBase = by * 256;

    int rr = lane & 15;
    int kq = (lane >> 4) * 8;
    int rbase = (lane >> 4) * 4;

    f32x4 acc[8][4];
    const f32x4 zero = {0.f, 0.f, 0.f, 0.f};
#pragma unroll
    for (int m = 0; m < 8; m++)
#pragma unroll
        for (int n = 0; n < 4; n++) acc[m][n] = zero;

    const unsigned short* gA0 = A + (size_t)(mBase + (wave * 2 + 0) * 16 + rr) * K + kq;
    const unsigned short* gA1 = A + (size_t)(mBase + (wave * 2 + 1) * 16 + rr) * K + kq;
    const unsigned short* gB0 = W + (size_t)(nBase + (wave * 2 + 0) * 16 + rr) * K + kq;
    const unsigned short* gB1 = W + (size_t)(nBase + (wave * 2 + 1) * 16 + rr) * K + kq;

    auto stage = [&](int b, int kt) {
        int ko = kt * 32;
        __builtin_amdgcn_global_load_lds((const AS1 void*)(gA0 + ko),
            (AS3 void*)(As + b * 8192 + (wave * 2 + 0) * 512), 16, 0, 0);
        __builtin_amdgcn_global_load_lds((const AS1 void*)(gA1 + ko),
            (AS3 void*)(As + b * 8192 + (wave * 2 + 1) * 512), 16, 0, 0);
        __builtin_amdgcn_global_load_lds((const AS1 void*)(gB0 + ko),
            (AS3 void*)(Bs + b * 8192 + (wave * 2 + 0) * 512), 16, 0, 0);
        __builtin_amdgcn_global_load_lds((const AS1 void*)(gB1 + ko),
            (AS3 void*)(Bs + b * 8192 + (wave * 2 + 1) * 512), 16, 0, 0);
    };

    int nt = K >> 5;
    stage(0, 0);

    for (int t = 0; t < nt; ++t) {
        int p = t & 1;
        if (t + 1 < nt) {
            stage(p ^ 1, t + 1);
            VMCNT4;
        } else {
            VMCNT0;
        }
        __builtin_amdgcn_s_barrier();
        __builtin_amdgcn_sched_barrier(0);

        bf16x8 af[8], bf[4];
#pragma unroll
        for (int m = 0; m < 8; m++)
            af[m] = *(const bf16x8*)(As + p * 8192 + (wm * 8 + m) * 512 + lane * 8);
#pragma unroll
        for (int n = 0; n < 4; n++)
            bf[n] = *(const bf16x8*)(Bs + p * 8192 + (wn * 4 + n) * 512 + lane * 8);
#pragma unroll
        for (int m = 0; m < 8; m++)
#pragma unroll
            for (int n = 0; n < 4; n++)
                acc[m][n] = __builtin_amdgcn_mfma_f32_16x16x32_bf16(af[m], bf[n], acc[m][n], 0, 0, 0);

        __builtin_amdgcn_sched_barrier(0);
        __builtin_amdgcn_s_barrier();
    }

    // ---- epilogue: 4 passes of 64 rows via LDS ----
    float bn[4];
#pragma unroll
    for (int n = 0; n < 4; n++)
        bn[n] = bias[nBase + wn * 64 + n * 16 + rr];

    int erow = tid >> 3;              // 0..63
    int ec0  = (tid & 7) * 32;        // 0..224
#pragma unroll
    for (int pass = 0; pass < 4; ++pass) {
        __syncthreads();
        if (wm == (pass >> 1)) {
#pragma unroll
            for (int mm = 0; mm < 4; ++mm) {
                int m = (pass & 1) * 4 + mm;
#pragma unroll
                for (int n = 0; n < 4; ++n) {
                    int lcol = wn * 64 + n * 16 + rr;
#pragma unroll
                    for (int r = 0; r < 4; ++r) {
                        float v = acc[m][n][r] + bn[n];
                        if (RELU) v = fmaxf(v, 0.f);
                        ebuf[(mm * 16 + rbase + r) * ES + lcol] = v;
                    }
                }
            }
        }
        __syncthreads();
        int grow = mBase + pass * 64 + erow;

        if constexpr (EPI == 0) {
            unsigned short* dst = (unsigned short*)Cout + (size_t)grow * N + nBase + ec0;
#pragma unroll
            for (int g = 0; g < 4; ++g) {
                u16x8 o;
#pragma unroll
                for (int j = 0; j < 8; ++j)
                    o[j] = f2bf(ebuf[erow * ES + ec0 + g * 8 + j]);
                *(u16x8*)(dst + g * 8) = o;
            }
        } else if constexpr (EPI == 1) {
            float* dst = (float*)Cout + (size_t)grow * N + nBase + ec0;
#pragma unroll
            for (int g = 0; g < 8; ++g)
                *(float4*)(dst + g * 4) = *(float4*)(ebuf + erow * ES + ec0 + g * 4);
        } else if constexpr (EPI == 2) {
            // x[v] = LN(ebuf + res1[v]) ; v = inds[grow]; dual f32 + bf16
            int v = inds[grow];
            const float* pr = res1 + (size_t)v * 256;
            f32x4 tv[8];
            float s = 0.f, s2 = 0.f;
#pragma unroll
            for (int g = 0; g < 8; ++g) {
                float4 e = *(float4*)(ebuf + erow * ES + ec0 + g * 4);
                float4 p = *(const float4*)(pr + ec0 + g * 4);
                f32x4 t = {e.x + p.x, e.y + p.y, e.z + p.z, e.w + p.w};
                tv[g] = t;
                s += t[0] + t[1] + t[2] + t[3];
                s2 += t[0]*t[0] + t[1]*t[1] + t[2]*t[2] + t[3]*t[3];
            }
#pragma unroll
            for (int off = 1; off < 8; off <<= 1) { s += __shfl_xor(s, off); s2 += __shfl_xor(s2, off); }
            float mean = s * (1.f/256.f);
            float var = fmaf(-mean, mean, s2 * (1.f/256.f));
            float rs = rsqrtf(var + 1e-5f);
            float* xd = (float*)Cout + (size_t)v * 256 + ec0;
            unsigned short* xb = out2 + (size_t)v * 256 + ec0;
#pragma unroll
            for (int g = 0; g < 8; ++g) {
                float4 gg = *(const float4*)(g1 + ec0 + g * 4);
                float4 bb = *(const float4*)(b1 + ec0 + g * 4);
                float4 o;
                o.x = fmaf((tv[g][0] - mean) * rs, gg.x, bb.x);
                o.y = fmaf((tv[g][1] - mean) * rs, gg.y, bb.y);
                o.z = fmaf((tv[g][2] - mean) * rs, gg.z, bb.z);
                o.w = fmaf((tv[g][3] - mean) * rs, gg.w, bb.w);
                *(float4*)(xd + g * 4) = o;
                ushort4 ob; ob.x = f2bf(o.x); ob.y = f2bf(o.y); ob.z = f2bf(o.z); ob.w = f2bf(o.w);
                *(ushort4*)(xb + g * 4) = ob;
            }
        } else {
            // out = LN( LN(ebuf + x, g1,b1) + prev, g2,b2 )
            const float* xr = res2 + (size_t)grow * 256;
            const float* pr = res1 + (size_t)grow * 256;
            f32x4 tv[8];
            float s = 0.f, s2 = 0.f;
#pragma unroll
            for (int g = 0; g < 8; ++g) {
                float4 e = *(float4*)(ebuf + erow * ES + ec0 + g * 4);
                float4 x = *(const float4*)(xr + ec0 + g * 4);
                f32x4 t = {e.x + x.x, e.y + x.y, e.z + x.z, e.w + x.w};
                tv[g] = t;
                s += t[0] + t[1] + t[2] + t[3];
                s2 += t[0]*t[0] + t[1]*t[1] + t[2]*t[2] + t[3]*t[3];
            }
#pragma unroll
            for (int off = 1; off < 8; off <<= 1) { s += __shfl_xor(s, off); s2 += __shfl_xor(s2, off); }
            float mean = s * (1.f/256.f);
            float var = fmaf(-mean, mean, s2 * (1.f/256.f));
            float rs = rsqrtf(var + 1e-5f);
            float s3 = 0.f, s4 = 0.f;
#pragma unroll
            for (int g = 0; g < 8; ++g) {
                float4 gg = *(const float4*)(g1 + ec0 + g * 4);
                float4 bb = *(const float4*)(b1 + ec0 + g * 4);
                float4 p = *(const float4*)(pr + ec0 + g * 4);
                f32x4 u;
                u[0] = fmaf((tv[g][0] - mean) * rs, gg.x, bb.x) + p.x;
                u[1] = fmaf((tv[g][1] - mean) * rs, gg.y, bb.y) + p.y;
                u[2] = fmaf((tv[g][2] - mean) * rs, gg.z, bb.z) + p.z;
                u[3] = fmaf((tv[g][3] - mean) * rs, gg.w, bb.w) + p.w;
                tv[g] = u;
                s3 += u[0] + u[1] + u[2] + u[3];
                s4 += u[0]*u[0] + u[1]*u[1] + u[2]*u[2] + u[3]*u[3];
            }
#pragma unroll
            for (int off = 1; off < 8; off <<= 1) { s3 += __shfl_xor(s3, off); s4 += __shfl_xor(s4, off); }
            float mean2 = s3 * (1.f/256.f);
            float var2 = fmaf(-mean2, mean2, s4 * (1.f/256.f));
            float rs2 = rsqrtf(var2 + 1e-5f);
            float* od = (float*)Cout + (size_t)grow * 256 + ec0;
#pragma unroll
            for (int g = 0; g < 8; ++g) {
                float4 gg = *(const float4*)(g2 + ec0 + g * 4);
                float4 bb = *(const float4*)(b2 + ec0 + g * 4);
                float4 o;
                o.x = fmaf((tv[g][0] - mean2) * rs2, gg.x, bb.x);
                o.y = fmaf((tv[g][1] - mean2) * rs2, gg.y, bb.y);
                o.z = fmaf((tv[g][2] - mean2) * rs2, gg.z, bb.z);
                o.w = fmaf((tv[g][3] - mean2) * rs2, gg.w, bb.w);
                *(float4*)(od + g * 4) = o;
            }
        }
    }
}

// ======================= MFMA attention ===========================
__global__ __launch_bounds__(256)
void attn_mfma_kernel(const unsigned short* __restrict__ QK,
                      const unsigned short* __restrict__ V,
                      const unsigned char* __restrict__ mask,
                      unsigned short* __restrict__ ao) {
    int s = blockIdx.x, h = blockIdx.y;
    int tid = threadIdx.x;
    int wq = tid >> 6;
    int lane = tid & 63;

    __shared__ alignas(16) unsigned short Ks[128 * 40];
    __shared__ alignas(16) unsigned short Vt[32 * 136];
    __shared__ alignas(16) unsigned short Plds[4 * 4096];
    __shared__ unsigned char msk[SSZ];

#pragma unroll
    for (int it = 0; it < 2; it++) {
        int idx = tid + it * 256;
        int key = idx >> 2, dimoff = (idx & 3) * 8;
        bf16x8 kv = *(const bf16x8*)(QK + (size_t)(s * SSZ + key) * 512 + 256 + h * HDIM + dimoff);
        *(bf16x8*)(Ks + key * 40 + dimoff) = kv;
        u16x8 vv = *(const u16x8*)(V + (size_t)(s * SSZ + key) * DM + h * HDIM + dimoff);
#pragma unroll
        for (int j = 0; j < 8; j++) Vt[(dimoff + j) * 136 + key] = vv[j];
    }
    if (tid < SSZ) msk[tid] = mask[s * SSZ + tid];
    __syncthreads();

    int rr = lane & 15;
    int kq = (lane >> 4) * 8;
    const f32x4 zero = {0.f, 0.f, 0.f, 0.f};

    bf16x8 qa[2];
#pragma unroll
    for (int mt = 0; mt < 2; mt++)
        qa[mt] = *(const bf16x8*)(QK + (size_t)(s * SSZ + wq * 32 + mt * 16 + rr) * 512 + h * HDIM + kq);

    f32x4 S[2][8];
#pragma unroll
    for (int nt = 0; nt < 8; nt++) {
        bf16x8 kb = *(const bf16x8*)(Ks + (nt * 16 + rr) * 40 + kq);
#pragma unroll
        for (int mt = 0; mt < 2; mt++)
            S[mt][nt] = __builtin_amdgcn_mfma_f32_16x16x32_bf16(qa[mt], kb, zero, 0, 0, 0);
    }

    const float SCALE = 0.17677669529663687f;
    f32x4 rm[2];
#pragma unroll
    for (int mt = 0; mt < 2; mt++) { rm[mt].x = rm[mt].y = rm[mt].z = rm[mt].w = -1e30f; }
#pragma unroll
    for (int nt = 0; nt < 8; nt++) {
        bool mv = msk[nt * 16 + rr] != 0;
#pragma unroll
        for (int mt = 0; mt < 2; mt++) {
#pragma unroll
            for (int r = 0; r < 4; r++) {
                float v = mv ? -1e30f : S[mt][nt][r] * SCALE;
                S[mt][nt][r] = v;
                rm[mt][r] = fmaxf(rm[mt][r], v);
            }
        }
    }
#pragma unroll
    for (int off = 1; off < 16; off <<= 1) {
#pragma unroll
        for (int mt = 0; mt < 2; mt++)
#pragma unroll
            for (int r = 0; r < 4; r++)
                rm[mt][r] = fmaxf(rm[mt][r], __shfl_xor(rm[mt][r], off));
    }

    f32x4 rs[2];
#pragma unroll
    for (int mt = 0; mt < 2; mt++) { rs[mt] = zero; }
#pragma unroll
    for (int nt = 0; nt < 8; nt++)
#pragma unroll
        for (int mt = 0; mt < 2; mt++)
#pragma unroll
            for (int r = 0; r < 4; r++) {
                float p = __expf(S[mt][nt][r] - rm[mt][r]);
                S[mt][nt][r] = p;
                rs[mt][r] += p;
            }
#pragma unroll
    for (int off = 1; off < 16; off <<= 1) {
#pragma unroll
        for (int mt = 0; mt < 2; mt++)
#pragma unroll
            for (int r = 0; r < 4; r++)
                rs[mt][r] += __shfl_xor(rs[mt][r], off);
    }

    char* Pbase = (char*)Plds + wq * 8192;
#pragma unroll
    for (int nt = 0; nt < 8; nt++)
#pragma unroll
        for (int mt = 0; mt < 2; mt++)
#pragma unroll
            for (int r = 0; r < 4; r++) {
                int prow = mt * 16 + (lane >> 4) * 4 + r;
                int col  = nt * 16 + rr;
                unsigned addr = (unsigned)(prow * 256 + col * 2) ^ ((prow & 7) << 4);
                *(unsigned short*)(Pbase + addr) = f2bf(S[mt][nt][r]);
            }
    __syncthreads();

    f32x4 O[2][2];
#pragma unroll
    for (int mt = 0; mt < 2; mt++)
#pragma unroll
        for (int nd = 0; nd < 2; nd++) O[mt][nd] = zero;
#pragma unroll
    for (int kc = 0; kc < 4; kc++) {
        bf16x8 pa[2];
#pragma unroll
        for (int mt = 0; mt < 2; mt++) {
            int prow = mt * 16 + rr;
            unsigned addr = (unsigned)(prow * 256 + (kc * 32 + kq) * 2) ^ ((prow & 7) << 4);
            pa[mt] = *(const bf16x8*)(Pbase + addr);
        }
#pragma unroll
        for (int nd = 0; nd < 2; nd++) {
            bf16x8 vb = *(const bf16x8*)(Vt + (nd * 16 + rr) * 136 + kc * 32 + kq);
#pragma unroll
            for (int mt = 0; mt < 2; mt++)
                O[mt][nd] = __builtin_amdgcn_mfma_f32_16x16x32_bf16(pa[mt], vb, O[mt][nd], 0, 0, 0);
        }
    }

#pragma unroll
    for (int mt = 0; mt < 2; mt++) {
#pragma unroll
        for (int nd = 0; nd < 2; nd++) {
#pragma unroll
            for (int r = 0; r < 4; r++) {
                int row = s * SSZ + wq * 32 + mt * 16 + (lane >> 4) * 4 + r;
                int col = h * HDIM + nd * 16 + rr;
                ao[(size_t)row * DM + col] = f2bf(O[mt][nd][r] / rs[mt][r]);
            }
        }
    }
}

// ============================= launch =============================
extern "C" void kernel_launch(void* const* d_in, const int* in_sizes, int n_in,
                              void* d_out, int out_size, void* d_ws, size_t ws_size,
                              hipStream_t stream) {
    const float* src       = (const float*)d_in[0];
    const float* pos_embed = (const float*)d_in[1];
    const int*   inds_all  = (const int*)d_in[2];
    const unsigned char* masks_all = (const unsigned char*)d_in[3];
    const float* w_qkv = (const float*)d_in[4];
    const float* b_qkv = (const float*)d_in[5];
    const float* w_out = (const float*)d_in[6];
    const float* b_out = (const float*)d_in[7];
    const float* w_ff1 = (const float*)d_in[8];
    const float* b_ff1 = (const float*)d_in[9];
    const float* w_ff2 = (const float*)d_in[10];
    const float* b_ff2 = (const float*)d_in[11];
    const float* g_n1 = (const float*)d_in[12];
    const float* b_n1 = (const float*)d_in[13];
    const float* g_n2 = (const float*)d_in[14];
    const float* b_n2 = (const float*)d_in[15];
    const float* g_ln = (const float*)d_in[16];
    const float* b_ln = (const float*)d_in[17];
    float* out = (float*)d_out;

    const size_t NVF = (size_t)NVOX * DM;  // 16,777,216
    unsigned short* A = (unsigned short*)d_ws;   // NVF u16: qk_bf -> ao_bf
    unsigned short* B = A + NVF;                 // NVF u16: feat_bf -> x_bf
    unsigned short* C = B + NVF;                 // 2*NVF u16: [Q|K]
    unsigned short* D = C + 2 * NVF;             // NVF u16: V bf16
    float* F = (float*)(D + NVF);                // NVF f32: x
    unsigned short* wts = (unsigned short*)(F + NVF);
    const size_t SZ_QKV = (size_t)2 * 3 * DM * DM;
    const size_t SZ_WO  = (size_t)2 * DM * DM;
    const size_t SZ_FF1 = (size_t)2 * DFFN * DM;
    const size_t SZ_FF2 = (size_t)2 * DM * DFFN;
    unsigned short* wqkv_bf = wts;
    unsigned short* wo_bf   = wqkv_bf + SZ_QKV;
    unsigned short* wff1_bf = wo_bf + SZ_WO;
    unsigned short* wff2_bf = wff1_bf + SZ_FF1;
    unsigned short* hbuf    = wff2_bf + SZ_FF2;

    size_t used_bytes = (char*)hbuf - (char*)d_ws;
    long long avail = (long long)ws_size - (long long)used_bytes;
    long long crows = avail / (DFFN * 2);
    if (crows > NVOX) crows = NVOX;
    crows &= ~2047LL;                      // grid.x multiple of 8 for swizzle
    int chunk = (crows < 2048) ? 2048 : (int)crows;

    cvt_bf16_kernel<<<512, 256, 0, stream>>>(w_qkv, wqkv_bf, (int)SZ_QKV);
    cvt_bf16_kernel<<<256, 256, 0, stream>>>(w_out, wo_bf, (int)SZ_WO);
    cvt_bf16_kernel<<<1024, 256, 0, stream>>>(w_ff1, wff1_bf, (int)SZ_FF1);
    cvt_bf16_kernel<<<1024, 256, 0, stream>>>(w_ff2, wff2_bf, (int)SZ_FF2);

    for (int i = 0; i < 2; i++) {
        const float* prev = (i == 0) ? src : out;
        const int* inds = inds_all + (size_t)i * 2 * SNUM * SSZ;
        const unsigned char* mask = masks_all + (size_t)i * 2 * SNUM * SSZ;
        const float* pos  = pos_embed + (size_t)i * NVF;
        const unsigned short* wqkv = wqkv_bf + (size_t)i * 3 * DM * DM;
        const unsigned short* wo   = wo_bf + (size_t)i * DM * DM;
        const unsigned short* wff1 = wff1_bf + (size_t)i * DFFN * DM;
        const unsigned short* wff2 = wff2_bf + (size_t)i * DM * DFFN;
        const float* bqkv = b_qkv + (size_t)i * 3 * DM;
        const float* bo   = b_out + (size_t)i * DM;
        const float* bff1 = b_ff1 + (size_t)i * DFFN;
        const float* bff2 = b_ff2 + (size_t)i * DM;

        gather_kernel<<<NVOX / 4, 256, 0, stream>>>(prev, pos, inds, A, B);

        // [Q|K] = qk @ [Wq;Wk]^T -> C (bf16)
        gemm_mfma256<0, false><<<dim3(NVOX / 256, 512 / 256), 512, 0, stream>>>(
            A, wqkv, bqkv, C, NVOX, 512, DM,
            nullptr, nullptr, nullptr, nullptr, nullptr, nullptr, nullptr, nullptr);
        // V = feat @ Wv^T -> D (bf16)
        gemm_mfma256<0, false><<<dim3(NVOX / 256, 1), 512, 0, stream>>>(
            B, wqkv + (size_t)512 * DM, bqkv + 512, D, NVOX, DM, DM,
            nullptr, nullptr, nullptr, nullptr, nullptr, nullptr, nullptr, nullptr);

        attn_mfma_kernel<<<dim3(SNUM, NH), 256, 0, stream>>>(C, D, mask, A);

        // Wo GEMM + fused LN1 scatter: x[v]=LN(a+prev[v]) -> F (f32) + B (bf16)
        gemm_mfma256<2, false><<<dim3(NVOX / 256, 1), 512, 0, stream>>>(
            A, wo, bo, F, NVOX, DM, DM,
            inds, prev, nullptr, g_n1 + i * DM, b_n1 + i * DM, nullptr, nullptr, B);

        // FFN: h = relu(x_bf@W1^T+b1) bf16; FF2 + fused LN2/LN3 -> out
        for (int r0 = 0; r0 < NVOX; r0 += chunk) {
            int rows = (NVOX - r0 < chunk) ? (NVOX - r0) : chunk;
            gemm_mfma256<0, true><<<dim3(rows / 256, DFFN / 256), 512, 0, stream>>>(
                B + (size_t)r0 * DM, wff1, bff1, hbuf, rows, DFFN, DM,
                nullptr, nullptr, nullptr, nullptr, nullptr, nullptr, nullptr, nullptr);
            gemm_mfma256<3, false><<<dim3(rows / 256, 1), 512, 0, stream>>>(
                hbuf, wff2, bff2, out + (size_t)r0 * DM, rows, DM, DFFN,
                nullptr, prev + (size_t)r0 * DM, F + (size_t)r0 * DM,
                g_n2 + i * DM, b_n2 + i * DM, g_ln + i * DM, b_ln + i * DM, nullptr);
        }
    }
}

// Round 8
// 1118.132 us; speedup vs baseline: 1.1904x; 1.0491x over previous
//
#include <hip/hip_runtime.h>
#include <math.h>

#define NVOX 65536
#define DM 256
#define NH 8
#define HDIM 32
#define DFFN 2048
#define SSZ 128
#define SNUM 512

#define AS1 __attribute__((address_space(1)))
#define AS3 __attribute__((address_space(3)))

typedef __attribute__((ext_vector_type(8))) __bf16 bf16x8;
typedef __attribute__((ext_vector_type(8))) unsigned short u16x8;
typedef __attribute__((ext_vector_type(4))) float f32x4;

__device__ __forceinline__ unsigned short f2bf(float f) {
    unsigned int u = __float_as_uint(f);
    u += 0x7fffu + ((u >> 16) & 1u);
    return (unsigned short)(u >> 16);
}
__device__ __forceinline__ float bf2f(unsigned short u) {
    return __uint_as_float(((unsigned int)u) << 16);
}

#define VMCNT0 asm volatile("s_waitcnt vmcnt(0)" ::: "memory")
#define VMCNT2 asm volatile("s_waitcnt vmcnt(2)" ::: "memory")
#define VMCNT3 asm volatile("s_waitcnt vmcnt(3)" ::: "memory")
#define VMCNT4 asm volatile("s_waitcnt vmcnt(4)" ::: "memory")
#define LGKM0  asm volatile("s_waitcnt lgkmcnt(0)" ::: "memory")

// ===================== weight fp32 -> bf16 ========================
__global__ __launch_bounds__(256)
void cvt_bf16_kernel(const float* __restrict__ in, unsigned short* __restrict__ out, int n) {
    int i = blockIdx.x * 256 + threadIdx.x;
    int stride = gridDim.x * 256;
    for (; i < n; i += stride) out[i] = f2bf(in[i]);
}

// ============================= gather =============================
__global__ __launch_bounds__(256)
void gather_kernel(const float* __restrict__ src, const float* __restrict__ pos,
                   const int* __restrict__ inds,
                   unsigned short* __restrict__ qk, unsigned short* __restrict__ feat) {
    int j = blockIdx.x * 4 + (threadIdx.x >> 6);
    int lane = threadIdx.x & 63;
    int v = inds[j];
    float4 a = ((const float4*)(src + (size_t)v * DM))[lane];
    float4 p = ((const float4*)(pos + (size_t)v * DM))[lane];
    ushort4 qo, fo;
    qo.x = f2bf(a.x + p.x); qo.y = f2bf(a.y + p.y);
    qo.z = f2bf(a.z + p.z); qo.w = f2bf(a.w + p.w);
    fo.x = f2bf(a.x); fo.y = f2bf(a.y); fo.z = f2bf(a.z); fo.w = f2bf(a.w);
    ((ushort4*)(qk   + (size_t)j * DM))[lane] = qo;
    ((ushort4*)(feat + (size_t)j * DM))[lane] = fo;
}

// ==================== 256x256 pipelined MFMA GEMM =================
// EPI 0: bf16 out (opt ReLU)   EPI 2: x=LN(ebuf+res1[inds[row]]) scatter f32+bf16
template<int EPI, bool RELU>
__global__ __launch_bounds__(512)
void gemm_mfma256(const unsigned short* __restrict__ A, const unsigned short* __restrict__ W,
                  const float* __restrict__ bias, void* __restrict__ Cout,
                  int M, int N, int K,
                  const int* __restrict__ inds,
                  const float* __restrict__ res1,
                  const float* __restrict__ g1, const float* __restrict__ b1,
                  unsigned short* __restrict__ out2) {
    __shared__ alignas(16) char smem[69632];
    unsigned short* As = (unsigned short*)smem;
    unsigned short* Bs = (unsigned short*)(smem + 32768);
    float* ebuf = (float*)smem;
    const int ES = 264;

    int tid = threadIdx.x;
    int wave = tid >> 6, lane = tid & 63;
    int wm = wave >> 2;
    int wn = wave & 3;

    unsigned lin = blockIdx.x + blockIdx.y * gridDim.x;
    unsigned nwg = gridDim.x * gridDim.y;
    unsigned swz = lin;
    if ((nwg & 7u) == 0u) { unsigned cpx = nwg >> 3; swz = (lin & 7u) * cpx + (lin >> 3); }
    int bx = (int)(swz / gridDim.y);
    int by = (int)(swz % gridDim.y);
    int mBase = bx * 256, nBase = by * 256;

    int rr = lane & 15;
    int kq = (lane >> 4) * 8;
    int rbase = (lane >> 4) * 4;

    f32x4 acc[8][4];
    const f32x4 zero = {0.f, 0.f, 0.f, 0.f};
#pragma unroll
    for (int m = 0; m < 8; m++)
#pragma unroll
        for (int n = 0; n < 4; n++) acc[m][n] = zero;

    const unsigned short* gA0 = A + (size_t)(mBase + (wave * 2 + 0) * 16 + rr) * K + kq;
    const unsigned short* gA1 = A + (size_t)(mBase + (wave * 2 + 1) * 16 + rr) * K + kq;
    const unsigned short* gB0 = W + (size_t)(nBase + (wave * 2 + 0) * 16 + rr) * K + kq;
    const unsigned short* gB1 = W + (size_t)(nBase + (wave * 2 + 1) * 16 + rr) * K + kq;

    auto stage = [&](int b, int kt) {
        int ko = kt * 32;
        __builtin_amdgcn_global_load_lds((const AS1 void*)(gA0 + ko),
            (AS3 void*)(As + b * 8192 + (wave * 2 + 0) * 512), 16, 0, 0);
        __builtin_amdgcn_global_load_lds((const AS1 void*)(gA1 + ko),
            (AS3 void*)(As + b * 8192 + (wave * 2 + 1) * 512), 16, 0, 0);
        __builtin_amdgcn_global_load_lds((const AS1 void*)(gB0 + ko),
            (AS3 void*)(Bs + b * 8192 + (wave * 2 + 0) * 512), 16, 0, 0);
        __builtin_amdgcn_global_load_lds((const AS1 void*)(gB1 + ko),
            (AS3 void*)(Bs + b * 8192 + (wave * 2 + 1) * 512), 16, 0, 0);
    };

    int nt = K >> 5;
    stage(0, 0);

    for (int t = 0; t < nt; ++t) {
        int p = t & 1;
        if (t + 1 < nt) { stage(p ^ 1, t + 1); VMCNT4; }
        else { VMCNT0; }
        __builtin_amdgcn_s_barrier();
        __builtin_amdgcn_sched_barrier(0);

        bf16x8 af[8], bf[4];
#pragma unroll
        for (int m = 0; m < 8; m++)
            af[m] = *(const bf16x8*)(As + p * 8192 + (wm * 8 + m) * 512 + lane * 8);
#pragma unroll
        for (int n = 0; n < 4; n++)
            bf[n] = *(const bf16x8*)(Bs + p * 8192 + (wn * 4 + n) * 512 + lane * 8);
#pragma unroll
        for (int m = 0; m < 8; m++)
#pragma unroll
            for (int n = 0; n < 4; n++)
                acc[m][n] = __builtin_amdgcn_mfma_f32_16x16x32_bf16(af[m], bf[n], acc[m][n], 0, 0, 0);

        __builtin_amdgcn_sched_barrier(0);
        __builtin_amdgcn_s_barrier();
    }

    float bn[4];
#pragma unroll
    for (int n = 0; n < 4; n++)
        bn[n] = bias[nBase + wn * 64 + n * 16 + rr];

    int erow = tid >> 3;
    int ec0  = (tid & 7) * 32;
#pragma unroll
    for (int pass = 0; pass < 4; ++pass) {
        __syncthreads();
        if (wm == (pass >> 1)) {
#pragma unroll
            for (int mm = 0; mm < 4; ++mm) {
                int m = (pass & 1) * 4 + mm;
#pragma unroll
                for (int n = 0; n < 4; ++n) {
                    int lcol = wn * 64 + n * 16 + rr;
#pragma unroll
                    for (int r = 0; r < 4; ++r) {
                        float v = acc[m][n][r] + bn[n];
                        if (RELU) v = fmaxf(v, 0.f);
                        ebuf[(mm * 16 + rbase + r) * ES + lcol] = v;
                    }
                }
            }
        }
        __syncthreads();
        int grow = mBase + pass * 64 + erow;

        if constexpr (EPI == 0) {
            unsigned short* dst = (unsigned short*)Cout + (size_t)grow * N + nBase + ec0;
#pragma unroll
            for (int g = 0; g < 4; ++g) {
                u16x8 o;
#pragma unroll
                for (int j = 0; j < 8; ++j)
                    o[j] = f2bf(ebuf[erow * ES + ec0 + g * 8 + j]);
                *(u16x8*)(dst + g * 8) = o;
            }
        } else {
            // x[v] = LN(ebuf + res1[v]); v = inds[grow]; dual f32 + bf16
            int v = inds[grow];
            const float* pr = res1 + (size_t)v * 256;
            f32x4 tv[8];
            float s = 0.f, s2 = 0.f;
#pragma unroll
            for (int g = 0; g < 8; ++g) {
                float4 e = *(float4*)(ebuf + erow * ES + ec0 + g * 4);
                float4 p = *(const float4*)(pr + ec0 + g * 4);
                f32x4 t = {e.x + p.x, e.y + p.y, e.z + p.z, e.w + p.w};
                tv[g] = t;
                s += t[0] + t[1] + t[2] + t[3];
                s2 += t[0]*t[0] + t[1]*t[1] + t[2]*t[2] + t[3]*t[3];
            }
#pragma unroll
            for (int off = 1; off < 8; off <<= 1) { s += __shfl_xor(s, off); s2 += __shfl_xor(s2, off); }
            float mean = s * (1.f/256.f);
            float var = fmaf(-mean, mean, s2 * (1.f/256.f));
            float rs = rsqrtf(var + 1e-5f);
            float* xd = (float*)Cout + (size_t)v * 256 + ec0;
            unsigned short* xb = out2 + (size_t)v * 256 + ec0;
#pragma unroll
            for (int g = 0; g < 8; ++g) {
                float4 gg = *(const float4*)(g1 + ec0 + g * 4);
                float4 bb = *(const float4*)(b1 + ec0 + g * 4);
                float4 o;
                o.x = fmaf((tv[g][0] - mean) * rs, gg.x, bb.x);
                o.y = fmaf((tv[g][1] - mean) * rs, gg.y, bb.y);
                o.z = fmaf((tv[g][2] - mean) * rs, gg.z, bb.z);
                o.w = fmaf((tv[g][3] - mean) * rs, gg.w, bb.w);
                *(float4*)(xd + g * 4) = o;
                ushort4 ob; ob.x = f2bf(o.x); ob.y = f2bf(o.y); ob.z = f2bf(o.z); ob.w = f2bf(o.w);
                *(ushort4*)(xb + g * 4) = ob;
            }
        }
    }
}

// ===================== fused FFN (FF1+FF2+LN2+LN3) =================
// Per block: 128 rows. h stays in LDS; y accumulates in regs across 8
// h-chunks of 256; W1/W2 stream in BK=32 slices (counted vmcnt, dbuf);
// x streams alongside W1. Epilogue: out = LN(LN(y+b2+x)+prev).
__global__ __launch_bounds__(512, 2)
void ffn_fused(const unsigned short* __restrict__ X,   // [NVOX][256] bf16 (x_bf)
               const unsigned short* __restrict__ W1,  // [2048][256] bf16
               const unsigned short* __restrict__ W2,  // [256][2048] bf16
               const float* __restrict__ b1g,          // [2048]
               const float* __restrict__ b2g,          // [256]
               const float* __restrict__ xf,           // [NVOX][256] f32 (res2)
               const float* __restrict__ prev,         // [NVOX][256] f32 (res1)
               const float* __restrict__ lnG1, const float* __restrict__ lnB1,
               const float* __restrict__ lnG2, const float* __restrict__ lnB2,
               float* __restrict__ out) {
    // LDS: Xbuf 2x8KB | Wbuf 2x16KB | Hs 64KB | B1s 8KB = 120KB
    __shared__ alignas(16) char smem[122880];
    unsigned short* Xbuf = (unsigned short*)smem;              // 2 x 4096 u16
    unsigned short* Wbuf = (unsigned short*)(smem + 16384);    // 2 x 8192 u16
    char*           HsB  = smem + 49152;                        // 128x256 u16 (swizzled)
    float*          B1s  = (float*)(smem + 114688);             // 2048 f32
    float*          ebuf = (float*)smem;                        // epilogue alias (16x264)
    const int ES = 264;

    int tid = threadIdx.x;
    int wave = tid >> 6, lane = tid & 63;
    int wm = wave >> 2;          // 0..1: rows wm*64..+64
    int wn = wave & 3;           // 0..3: cols wn*64..+64
    int mBase = blockIdx.x * 128;
    int rr = lane & 15;
    int kq = (lane >> 4) * 8;
    int rbase = (lane >> 4) * 4;

    // stage b1 to LDS (drained by the syncthreads below)
    {
        float4 bv = *(const float4*)(b1g + tid * 4);
        *(float4*)(B1s + tid * 4) = bv;
    }
    __syncthreads();  // vmcnt(0)+lgkmcnt(0): b1 loads done before counted pipeline starts

    auto gll = [&](const unsigned short* g, unsigned short* l) {
        __builtin_amdgcn_global_load_lds((const AS1 void*)g, (AS3 void*)l, 16, 0, 0);
    };
    // slice s (0..127): c=s>>4, half=(s>>3)&1, kt=s&7.
    // half0 (FF1): 1 x-load + 2 W1-loads per wave; half1 (FF2): 2 W2-loads.
    auto stage_slice = [&](int s) {
        int c = s >> 4, half = (s >> 3) & 1, kt = s & 7;
        unsigned short* wb = Wbuf + (s & 1) * 8192;
        if (half == 0) {
            gll(X + (size_t)(mBase + wave * 16 + rr) * 256 + kt * 32 + kq,
                Xbuf + (kt & 1) * 4096 + wave * 512);
            gll(W1 + (size_t)(c * 256 + (wave * 2 + 0) * 16 + rr) * 256 + kt * 32 + kq,
                wb + (wave * 2 + 0) * 512);
            gll(W1 + (size_t)(c * 256 + (wave * 2 + 1) * 16 + rr) * 256 + kt * 32 + kq,
                wb + (wave * 2 + 1) * 512);
        } else {
            gll(W2 + (size_t)((wave * 2 + 0) * 16 + rr) * 2048 + c * 256 + kt * 32 + kq,
                wb + (wave * 2 + 0) * 512);
            gll(W2 + (size_t)((wave * 2 + 1) * 16 + rr) * 2048 + c * 256 + kt * 32 + kq,
                wb + (wave * 2 + 1) * 512);
        }
    };

    f32x4 yacc[4][4];
    const f32x4 zero = {0.f, 0.f, 0.f, 0.f};
#pragma unroll
    for (int m = 0; m < 4; m++)
#pragma unroll
        for (int n = 0; n < 4; n++) yacc[m][n] = zero;

    stage_slice(0);

    for (int c = 0; c < 8; ++c) {
        f32x4 hacc[4][4];
#pragma unroll
        for (int m = 0; m < 4; m++)
#pragma unroll
            for (int n = 0; n < 4; n++) hacc[m][n] = zero;

        // ---- FF1: 8 K-steps over x (K=256) ----
#pragma unroll
        for (int kt = 0; kt < 8; ++kt) {
            int s = c * 16 + kt;
            stage_slice(s + 1);
            if (kt < 7) VMCNT3; else VMCNT2;
            __builtin_amdgcn_s_barrier();
            __builtin_amdgcn_sched_barrier(0);

            bf16x8 af[4], bf[4];
#pragma unroll
            for (int m = 0; m < 4; m++)
                af[m] = *(const bf16x8*)(Xbuf + (kt & 1) * 4096 + (wm * 4 + m) * 512 + lane * 8);
#pragma unroll
            for (int n = 0; n < 4; n++)
                bf[n] = *(const bf16x8*)(Wbuf + (s & 1) * 8192 + (wn * 4 + n) * 512 + lane * 8);
#pragma unroll
            for (int m = 0; m < 4; m++)
#pragma unroll
                for (int n = 0; n < 4; n++)
                    hacc[m][n] = __builtin_amdgcn_mfma_f32_16x16x32_bf16(af[m], bf[n], hacc[m][n], 0, 0, 0);

            __builtin_amdgcn_sched_barrier(0);
            __builtin_amdgcn_s_barrier();
        }

        // ---- write Hc (relu(hacc+b1)) to swizzled LDS ----
        {
            float b1v[4];
#pragma unroll
            for (int n = 0; n < 4; n++)
                b1v[n] = B1s[c * 256 + wn * 64 + n * 16 + rr];
#pragma unroll
            for (int m = 0; m < 4; m++)
#pragma unroll
                for (int n = 0; n < 4; n++)
#pragma unroll
                    for (int r = 0; r < 4; r++) {
                        float v = fmaxf(hacc[m][n][r] + b1v[n], 0.f);
                        int row = wm * 64 + m * 16 + rbase + r;
                        int col = wn * 64 + n * 16 + rr;
                        unsigned byte = (unsigned)(row * 512 + col * 2) ^ ((row & 7) << 4);
                        *(unsigned short*)(HsB + byte) = f2bf(v);
                    }
            LGKM0;
            __builtin_amdgcn_s_barrier();
        }

        // ---- FF2: 8 K-steps over Hc chunk (K=256), accumulate y ----
#pragma unroll
        for (int kt = 0; kt < 8; ++kt) {
            int s = c * 16 + 8 + kt;
            if (s + 1 < 128) stage_slice(s + 1);
            if (s + 1 >= 128) { VMCNT0; }
            else if (kt < 7) { VMCNT2; }
            else { VMCNT3; }
            __builtin_amdgcn_s_barrier();
            __builtin_amdgcn_sched_barrier(0);

            bf16x8 af[4], bf[4];
#pragma unroll
            for (int m = 0; m < 4; m++) {
                int row = wm * 64 + m * 16 + rr;
                unsigned byte = (unsigned)(row * 512 + kt * 64 + (lane >> 4) * 16) ^ ((rr & 7) << 4);
                af[m] = *(const bf16x8*)(HsB + byte);
            }
#pragma unroll
            for (int n = 0; n < 4; n++)
                bf[n] = *(const bf16x8*)(Wbuf + (s & 1) * 8192 + (wn * 4 + n) * 512 + lane * 8);
#pragma unroll
            for (int m = 0; m < 4; m++)
#pragma unroll
                for (int n = 0; n < 4; n++)
                    yacc[m][n] = __builtin_amdgcn_mfma_f32_16x16x32_bf16(af[m], bf[n], yacc[m][n], 0, 0, 0);

            __builtin_amdgcn_sched_barrier(0);
            __builtin_amdgcn_s_barrier();
        }
    }

    // ---- epilogue: out = LN( LN(y + b2 + x) + prev ), 8 passes x 16 rows ----
    float b2v[4];
#pragma unroll
    for (int n = 0; n < 4; n++)
        b2v[n] = b2g[wn * 64 + n * 16 + rr];

    int erow = tid >> 5;              // 0..15
    int ec0  = (tid & 31) * 8;        // 0..248
#pragma unroll
    for (int p = 0; p < 8; ++p) {
        __syncthreads();
        if (wm == (p >> 2)) {
            const int m = p & 3;
#pragma unroll
            for (int n = 0; n < 4; ++n) {
                int lcol = wn * 64 + n * 16 + rr;
#pragma unroll
                for (int r = 0; r < 4; ++r)
                    ebuf[(rbase + r) * ES + lcol] = yacc[m][n][r] + b2v[n];
            }
        }
        __syncthreads();
        int grow = mBase + p * 16 + erow;

        float tv[8];
        float s1 = 0.f, s2 = 0.f;
        const float* xr = xf + (size_t)grow * 256 + ec0;
#pragma unroll
        for (int j = 0; j < 8; ++j) {
            float t = ebuf[erow * ES + ec0 + j] + xr[j];
            tv[j] = t; s1 += t; s2 += t * t;
        }
#pragma unroll
        for (int off = 1; off < 32; off <<= 1) { s1 += __shfl_xor(s1, off); s2 += __shfl_xor(s2, off); }
        float mean = s1 * (1.f/256.f);
        float var = fmaf(-mean, mean, s2 * (1.f/256.f));
        float rs = rsqrtf(var + 1e-5f);

        const float* pr = prev + (size_t)grow * 256 + ec0;
        float s3 = 0.f, s4 = 0.f;
#pragma unroll
        for (int j = 0; j < 8; ++j) {
            float u = fmaf((tv[j] - mean) * rs, lnG1[ec0 + j], lnB1[ec0 + j]) + pr[j];
            tv[j] = u; s3 += u; s4 += u * u;
        }
#pragma unroll
        for (int off = 1; off < 32; off <<= 1) { s3 += __shfl_xor(s3, off); s4 += __shfl_xor(s4, off); }
        float mean2 = s3 * (1.f/256.f);
        float var2 = fmaf(-mean2, mean2, s4 * (1.f/256.f));
        float rs2 = rsqrtf(var2 + 1e-5f);

        float* od = out + (size_t)grow * 256 + ec0;
#pragma unroll
        for (int g = 0; g < 2; ++g) {
            float4 o;
            o.x = fmaf((tv[g*4+0] - mean2) * rs2, lnG2[ec0 + g*4+0], lnB2[ec0 + g*4+0]);
            o.y = fmaf((tv[g*4+1] - mean2) * rs2, lnG2[ec0 + g*4+1], lnB2[ec0 + g*4+1]);
            o.z = fmaf((tv[g*4+2] - mean2) * rs2, lnG2[ec0 + g*4+2], lnB2[ec0 + g*4+2]);
            o.w = fmaf((tv[g*4+3] - mean2) * rs2, lnG2[ec0 + g*4+3], lnB2[ec0 + g*4+3]);
            *(float4*)(od + g * 4) = o;
        }
    }
}

// ======================= MFMA attention ===========================
__global__ __launch_bounds__(256)
void attn_mfma_kernel(const unsigned short* __restrict__ QK,
                      const unsigned short* __restrict__ V,
                      const unsigned char* __restrict__ mask,
                      unsigned short* __restrict__ ao) {
    int s = blockIdx.x, h = blockIdx.y;
    int tid = threadIdx.x;
    int wq = tid >> 6;
    int lane = tid & 63;

    __shared__ alignas(16) unsigned short Ks[128 * 40];
    __shared__ alignas(16) unsigned short Vt[32 * 136];
    __shared__ alignas(16) unsigned short Plds[4 * 4096];
    __shared__ unsigned char msk[SSZ];

#pragma unroll
    for (int it = 0; it < 2; it++) {
        int idx = tid + it * 256;
        int key = idx >> 2, dimoff = (idx & 3) * 8;
        bf16x8 kv = *(const bf16x8*)(QK + (size_t)(s * SSZ + key) * 512 + 256 + h * HDIM + dimoff);
        *(bf16x8*)(Ks + key * 40 + dimoff) = kv;
        u16x8 vv = *(const u16x8*)(V + (size_t)(s * SSZ + key) * DM + h * HDIM + dimoff);
#pragma unroll
        for (int j = 0; j < 8; j++) Vt[(dimoff + j) * 136 + key] = vv[j];
    }
    if (tid < SSZ) msk[tid] = mask[s * SSZ + tid];
    __syncthreads();

    int rr = lane & 15;
    int kq = (lane >> 4) * 8;
    const f32x4 zero = {0.f, 0.f, 0.f, 0.f};

    bf16x8 qa[2];
#pragma unroll
    for (int mt = 0; mt < 2; mt++)
        qa[mt] = *(const bf16x8*)(QK + (size_t)(s * SSZ + wq * 32 + mt * 16 + rr) * 512 + h * HDIM + kq);

    f32x4 S[2][8];
#pragma unroll
    for (int nt = 0; nt < 8; nt++) {
        bf16x8 kb = *(const bf16x8*)(Ks + (nt * 16 + rr) * 40 + kq);
#pragma unroll
        for (int mt = 0; mt < 2; mt++)
            S[mt][nt] = __builtin_amdgcn_mfma_f32_16x16x32_bf16(qa[mt], kb, zero, 0, 0, 0);
    }

    const float SCALE = 0.17677669529663687f;
    f32x4 rm[2];
#pragma unroll
    for (int mt = 0; mt < 2; mt++) { rm[mt].x = rm[mt].y = rm[mt].z = rm[mt].w = -1e30f; }
#pragma unroll
    for (int nt = 0; nt < 8; nt++) {
        bool mv = msk[nt * 16 + rr] != 0;
#pragma unroll
        for (int mt = 0; mt < 2; mt++) {
#pragma unroll
            for (int r = 0; r < 4; r++) {
                float v = mv ? -1e30f : S[mt][nt][r] * SCALE;
                S[mt][nt][r] = v;
                rm[mt][r] = fmaxf(rm[mt][r], v);
            }
        }
    }
#pragma unroll
    for (int off = 1; off < 16; off <<= 1) {
#pragma unroll
        for (int mt = 0; mt < 2; mt++)
#pragma unroll
            for (int r = 0; r < 4; r++)
                rm[mt][r] = fmaxf(rm[mt][r], __shfl_xor(rm[mt][r], off));
    }

    f32x4 rs[2];
#pragma unroll
    for (int mt = 0; mt < 2; mt++) { rs[mt] = zero; }
#pragma unroll
    for (int nt = 0; nt < 8; nt++)
#pragma unroll
        for (int mt = 0; mt < 2; mt++)
#pragma unroll
            for (int r = 0; r < 4; r++) {
                float p = __expf(S[mt][nt][r] - rm[mt][r]);
                S[mt][nt][r] = p;
                rs[mt][r] += p;
            }
#pragma unroll
    for (int off = 1; off < 16; off <<= 1) {
#pragma unroll
        for (int mt = 0; mt < 2; mt++)
#pragma unroll
            for (int r = 0; r < 4; r++)
                rs[mt][r] += __shfl_xor(rs[mt][r], off);
    }

    char* Pbase = (char*)Plds + wq * 8192;
#pragma unroll
    for (int nt = 0; nt < 8; nt++)
#pragma unroll
        for (int mt = 0; mt < 2; mt++)
#pragma unroll
            for (int r = 0; r < 4; r++) {
                int prow = mt * 16 + (lane >> 4) * 4 + r;
                int col  = nt * 16 + rr;
                unsigned addr = (unsigned)(prow * 256 + col * 2) ^ ((prow & 7) << 4);
                *(unsigned short*)(Pbase + addr) = f2bf(S[mt][nt][r]);
            }
    __syncthreads();

    f32x4 O[2][2];
#pragma unroll
    for (int mt = 0; mt < 2; mt++)
#pragma unroll
        for (int nd = 0; nd < 2; nd++) O[mt][nd] = zero;
#pragma unroll
    for (int kc = 0; kc < 4; kc++) {
        bf16x8 pa[2];
#pragma unroll
        for (int mt = 0; mt < 2; mt++) {
            int prow = mt * 16 + rr;
            unsigned addr = (unsigned)(prow * 256 + (kc * 32 + kq) * 2) ^ ((prow & 7) << 4);
            pa[mt] = *(const bf16x8*)(Pbase + addr);
        }
#pragma unroll
        for (int nd = 0; nd < 2; nd++) {
            bf16x8 vb = *(const bf16x8*)(Vt + (nd * 16 + rr) * 136 + kc * 32 + kq);
#pragma unroll
            for (int mt = 0; mt < 2; mt++)
                O[mt][nd] = __builtin_amdgcn_mfma_f32_16x16x32_bf16(pa[mt], vb, O[mt][nd], 0, 0, 0);
        }
    }

#pragma unroll
    for (int mt = 0; mt < 2; mt++) {
#pragma unroll
        for (int nd = 0; nd < 2; nd++) {
#pragma unroll
            for (int r = 0; r < 4; r++) {
                int row = s * SSZ + wq * 32 + mt * 16 + (lane >> 4) * 4 + r;
                int col = h * HDIM + nd * 16 + rr;
                ao[(size_t)row * DM + col] = f2bf(O[mt][nd][r] / rs[mt][r]);
            }
        }
    }
}

// ============================= launch =============================
extern "C" void kernel_launch(void* const* d_in, const int* in_sizes, int n_in,
                              void* d_out, int out_size, void* d_ws, size_t ws_size,
                              hipStream_t stream) {
    const float* src       = (const float*)d_in[0];
    const float* pos_embed = (const float*)d_in[1];
    const int*   inds_all  = (const int*)d_in[2];
    const unsigned char* masks_all = (const unsigned char*)d_in[3];
    const float* w_qkv = (const float*)d_in[4];
    const float* b_qkv = (const float*)d_in[5];
    const float* w_out = (const float*)d_in[6];
    const float* b_out = (const float*)d_in[7];
    const float* w_ff1 = (const float*)d_in[8];
    const float* b_ff1 = (const float*)d_in[9];
    const float* w_ff2 = (const float*)d_in[10];
    const float* b_ff2 = (const float*)d_in[11];
    const float* g_n1 = (const float*)d_in[12];
    const float* b_n1 = (const float*)d_in[13];
    const float* g_n2 = (const float*)d_in[14];
    const float* b_n2 = (const float*)d_in[15];
    const float* g_ln = (const float*)d_in[16];
    const float* b_ln = (const float*)d_in[17];
    float* out = (float*)d_out;

    const size_t NVF = (size_t)NVOX * DM;  // 16,777,216
    unsigned short* A = (unsigned short*)d_ws;   // NVF u16: qk_bf -> ao_bf
    unsigned short* B = A + NVF;                 // NVF u16: feat_bf -> x_bf
    unsigned short* C = B + NVF;                 // 2*NVF u16: [Q|K]
    unsigned short* D = C + 2 * NVF;             // NVF u16: V bf16
    float* F = (float*)(D + NVF);                // NVF f32: x
    unsigned short* wts = (unsigned short*)(F + NVF);
    const size_t SZ_QKV = (size_t)2 * 3 * DM * DM;
    const size_t SZ_WO  = (size_t)2 * DM * DM;
    const size_t SZ_FF1 = (size_t)2 * DFFN * DM;
    const size_t SZ_FF2 = (size_t)2 * DM * DFFN;
    unsigned short* wqkv_bf = wts;
    unsigned short* wo_bf   = wqkv_bf + SZ_QKV;
    unsigned short* wff1_bf = wo_bf + SZ_WO;
    unsigned short* wff2_bf = wff1_bf + SZ_FF1;

    cvt_bf16_kernel<<<512, 256, 0, stream>>>(w_qkv, wqkv_bf, (int)SZ_QKV);
    cvt_bf16_kernel<<<256, 256, 0, stream>>>(w_out, wo_bf, (int)SZ_WO);
    cvt_bf16_kernel<<<1024, 256, 0, stream>>>(w_ff1, wff1_bf, (int)SZ_FF1);
    cvt_bf16_kernel<<<1024, 256, 0, stream>>>(w_ff2, wff2_bf, (int)SZ_FF2);

    for (int i = 0; i < 2; i++) {
        const float* prev = (i == 0) ? src : out;
        const int* inds = inds_all + (size_t)i * 2 * SNUM * SSZ;
        const unsigned char* mask = masks_all + (size_t)i * 2 * SNUM * SSZ;
        const float* pos  = pos_embed + (size_t)i * NVF;
        const unsigned short* wqkv = wqkv_bf + (size_t)i * 3 * DM * DM;
        const unsigned short* wo   = wo_bf + (size_t)i * DM * DM;
        const unsigned short* wff1 = wff1_bf + (size_t)i * DFFN * DM;
        const unsigned short* wff2 = wff2_bf + (size_t)i * DM * DFFN;
        const float* bqkv = b_qkv + (size_t)i * 3 * DM;
        const float* bo   = b_out + (size_t)i * DM;
        const float* bff1 = b_ff1 + (size_t)i * DFFN;
        const float* bff2 = b_ff2 + (size_t)i * DM;

        gather_kernel<<<NVOX / 4, 256, 0, stream>>>(prev, pos, inds, A, B);

        // [Q|K] = qk @ [Wq;Wk]^T -> C (bf16)
        gemm_mfma256<0, false><<<dim3(NVOX / 256, 512 / 256), 512, 0, stream>>>(
            A, wqkv, bqkv, C, NVOX, 512, DM,
            nullptr, nullptr, nullptr, nullptr, nullptr);
        // V = feat @ Wv^T -> D (bf16)
        gemm_mfma256<0, false><<<dim3(NVOX / 256, 1), 512, 0, stream>>>(
            B, wqkv + (size_t)512 * DM, bqkv + 512, D, NVOX, DM, DM,
            nullptr, nullptr, nullptr, nullptr, nullptr);

        attn_mfma_kernel<<<dim3(SNUM, NH), 256, 0, stream>>>(C, D, mask, A);

        // Wo GEMM + fused LN1 scatter: x[v]=LN(a+prev[v]) -> F (f32) + B (bf16)
        gemm_mfma256<2, false><<<dim3(NVOX / 256, 1), 512, 0, stream>>>(
            A, wo, bo, F, NVOX, DM, DM,
            inds, prev, g_n1 + i * DM, b_n1 + i * DM, B);

        // fused FFN + LN2 + LN3 -> out
        ffn_fused<<<dim3(NVOX / 128), 512, 0, stream>>>(
            B, wff1, wff2, bff1, bff2, F, prev,
            g_n2 + i * DM, b_n2 + i * DM, g_ln + i * DM, b_ln + i * DM, out);
    }
}

// Round 9
// 1023.343 us; speedup vs baseline: 1.3007x; 1.0926x over previous
//
#include <hip/hip_runtime.h>
#include <math.h>

#define NVOX 65536
#define DM 256
#define NH 8
#define HDIM 32
#define DFFN 2048
#define SSZ 128
#define SNUM 512

#define AS1 __attribute__((address_space(1)))
#define AS3 __attribute__((address_space(3)))

typedef __attribute__((ext_vector_type(8))) __bf16 bf16x8;
typedef __attribute__((ext_vector_type(8))) unsigned short u16x8;
typedef __attribute__((ext_vector_type(4))) float f32x4;

__device__ __forceinline__ unsigned short f2bf(float f) {
    unsigned int u = __float_as_uint(f);
    u += 0x7fffu + ((u >> 16) & 1u);
    return (unsigned short)(u >> 16);
}
__device__ __forceinline__ float bf2f(unsigned short u) {
    return __uint_as_float(((unsigned int)u) << 16);
}

#define VMCNT0 asm volatile("s_waitcnt vmcnt(0)" ::: "memory")
#define VMCNT2 asm volatile("s_waitcnt vmcnt(2)" ::: "memory")
#define VMCNT4 asm volatile("s_waitcnt vmcnt(4)" ::: "memory")
#define LGKM0  asm volatile("s_waitcnt lgkmcnt(0)" ::: "memory")

// ===================== weight fp32 -> bf16 ========================
__global__ __launch_bounds__(256)
void cvt_bf16_kernel(const float* __restrict__ in, unsigned short* __restrict__ out, int n) {
    int i = blockIdx.x * 256 + threadIdx.x;
    int stride = gridDim.x * 256;
    for (; i < n; i += stride) out[i] = f2bf(in[i]);
}

// ============================= gather =============================
__global__ __launch_bounds__(256)
void gather_kernel(const float* __restrict__ src, const float* __restrict__ pos,
                   const int* __restrict__ inds,
                   unsigned short* __restrict__ qk, unsigned short* __restrict__ feat) {
    int j = blockIdx.x * 4 + (threadIdx.x >> 6);
    int lane = threadIdx.x & 63;
    int v = inds[j];
    float4 a = ((const float4*)(src + (size_t)v * DM))[lane];
    float4 p = ((const float4*)(pos + (size_t)v * DM))[lane];
    ushort4 qo, fo;
    qo.x = f2bf(a.x + p.x); qo.y = f2bf(a.y + p.y);
    qo.z = f2bf(a.z + p.z); qo.w = f2bf(a.w + p.w);
    fo.x = f2bf(a.x); fo.y = f2bf(a.y); fo.z = f2bf(a.z); fo.w = f2bf(a.w);
    ((ushort4*)(qk   + (size_t)j * DM))[lane] = qo;
    ((ushort4*)(feat + (size_t)j * DM))[lane] = fo;
}

// ==================== 256x256 pipelined MFMA GEMM =================
// EPI 0: bf16 out (opt ReLU)   EPI 2: x=LN(ebuf+res1[inds[row]]) scatter f32+bf16
template<int EPI, bool RELU>
__global__ __launch_bounds__(512)
void gemm_mfma256(const unsigned short* __restrict__ A, const unsigned short* __restrict__ W,
                  const float* __restrict__ bias, void* __restrict__ Cout,
                  int M, int N, int K,
                  const int* __restrict__ inds,
                  const float* __restrict__ res1,
                  const float* __restrict__ g1, const float* __restrict__ b1,
                  unsigned short* __restrict__ out2) {
    __shared__ alignas(16) char smem[69632];
    unsigned short* As = (unsigned short*)smem;
    unsigned short* Bs = (unsigned short*)(smem + 32768);
    float* ebuf = (float*)smem;
    const int ES = 264;

    int tid = threadIdx.x;
    int wave = tid >> 6, lane = tid & 63;
    int wm = wave >> 2;
    int wn = wave & 3;

    unsigned lin = blockIdx.x + blockIdx.y * gridDim.x;
    unsigned nwg = gridDim.x * gridDim.y;
    unsigned swz = lin;
    if ((nwg & 7u) == 0u) { unsigned cpx = nwg >> 3; swz = (lin & 7u) * cpx + (lin >> 3); }
    int bx = (int)(swz / gridDim.y);
    int by = (int)(swz % gridDim.y);
    int mBase = bx * 256, nBase = by * 256;

    int rr = lane & 15;
    int kq = (lane >> 4) * 8;
    int rbase = (lane >> 4) * 4;

    f32x4 acc[8][4];
    const f32x4 zero = {0.f, 0.f, 0.f, 0.f};
#pragma unroll
    for (int m = 0; m < 8; m++)
#pragma unroll
        for (int n = 0; n < 4; n++) acc[m][n] = zero;

    const unsigned short* gA0 = A + (size_t)(mBase + (wave * 2 + 0) * 16 + rr) * K + kq;
    const unsigned short* gA1 = A + (size_t)(mBase + (wave * 2 + 1) * 16 + rr) * K + kq;
    const unsigned short* gB0 = W + (size_t)(nBase + (wave * 2 + 0) * 16 + rr) * K + kq;
    const unsigned short* gB1 = W + (size_t)(nBase + (wave * 2 + 1) * 16 + rr) * K + kq;

    auto stage = [&](int b, int kt) {
        int ko = kt * 32;
        __builtin_amdgcn_global_load_lds((const AS1 void*)(gA0 + ko),
            (AS3 void*)(As + b * 8192 + (wave * 2 + 0) * 512), 16, 0, 0);
        __builtin_amdgcn_global_load_lds((const AS1 void*)(gA1 + ko),
            (AS3 void*)(As + b * 8192 + (wave * 2 + 1) * 512), 16, 0, 0);
        __builtin_amdgcn_global_load_lds((const AS1 void*)(gB0 + ko),
            (AS3 void*)(Bs + b * 8192 + (wave * 2 + 0) * 512), 16, 0, 0);
        __builtin_amdgcn_global_load_lds((const AS1 void*)(gB1 + ko),
            (AS3 void*)(Bs + b * 8192 + (wave * 2 + 1) * 512), 16, 0, 0);
    };

    int nt = K >> 5;
    stage(0, 0);

    for (int t = 0; t < nt; ++t) {
        int p = t & 1;
        if (t + 1 < nt) { stage(p ^ 1, t + 1); VMCNT4; }
        else { VMCNT0; }
        __builtin_amdgcn_s_barrier();
        __builtin_amdgcn_sched_barrier(0);

        bf16x8 af[8], bf[4];
#pragma unroll
        for (int m = 0; m < 8; m++)
            af[m] = *(const bf16x8*)(As + p * 8192 + (wm * 8 + m) * 512 + lane * 8);
#pragma unroll
        for (int n = 0; n < 4; n++)
            bf[n] = *(const bf16x8*)(Bs + p * 8192 + (wn * 4 + n) * 512 + lane * 8);
#pragma unroll
        for (int m = 0; m < 8; m++)
#pragma unroll
            for (int n = 0; n < 4; n++)
                acc[m][n] = __builtin_amdgcn_mfma_f32_16x16x32_bf16(af[m], bf[n], acc[m][n], 0, 0, 0);

        __builtin_amdgcn_sched_barrier(0);
        __builtin_amdgcn_s_barrier();
    }

    float bn[4];
#pragma unroll
    for (int n = 0; n < 4; n++)
        bn[n] = bias[nBase + wn * 64 + n * 16 + rr];

    int erow = tid >> 3;
    int ec0  = (tid & 7) * 32;
#pragma unroll
    for (int pass = 0; pass < 4; ++pass) {
        __syncthreads();
        if (wm == (pass >> 1)) {
#pragma unroll
            for (int mm = 0; mm < 4; ++mm) {
                int m = (pass & 1) * 4 + mm;
#pragma unroll
                for (int n = 0; n < 4; ++n) {
                    int lcol = wn * 64 + n * 16 + rr;
#pragma unroll
                    for (int r = 0; r < 4; ++r) {
                        float v = acc[m][n][r] + bn[n];
                        if (RELU) v = fmaxf(v, 0.f);
                        ebuf[(mm * 16 + rbase + r) * ES + lcol] = v;
                    }
                }
            }
        }
        __syncthreads();
        int grow = mBase + pass * 64 + erow;

        if constexpr (EPI == 0) {
            unsigned short* dst = (unsigned short*)Cout + (size_t)grow * N + nBase + ec0;
#pragma unroll
            for (int g = 0; g < 4; ++g) {
                u16x8 o;
#pragma unroll
                for (int j = 0; j < 8; ++j)
                    o[j] = f2bf(ebuf[erow * ES + ec0 + g * 8 + j]);
                *(u16x8*)(dst + g * 8) = o;
            }
        } else {
            int v = inds[grow];
            const float* pr = res1 + (size_t)v * 256;
            f32x4 tv[8];
            float s = 0.f, s2 = 0.f;
#pragma unroll
            for (int g = 0; g < 8; ++g) {
                float4 e = *(float4*)(ebuf + erow * ES + ec0 + g * 4);
                float4 p = *(const float4*)(pr + ec0 + g * 4);
                f32x4 t = {e.x + p.x, e.y + p.y, e.z + p.z, e.w + p.w};
                tv[g] = t;
                s += t[0] + t[1] + t[2] + t[3];
                s2 += t[0]*t[0] + t[1]*t[1] + t[2]*t[2] + t[3]*t[3];
            }
#pragma unroll
            for (int off = 1; off < 8; off <<= 1) { s += __shfl_xor(s, off); s2 += __shfl_xor(s2, off); }
            float mean = s * (1.f/256.f);
            float var = fmaf(-mean, mean, s2 * (1.f/256.f));
            float rs = rsqrtf(var + 1e-5f);
            float* xd = (float*)Cout + (size_t)v * 256 + ec0;
            unsigned short* xb = out2 + (size_t)v * 256 + ec0;
#pragma unroll
            for (int g = 0; g < 8; ++g) {
                float4 gg = *(const float4*)(g1 + ec0 + g * 4);
                float4 bb = *(const float4*)(b1 + ec0 + g * 4);
                float4 o;
                o.x = fmaf((tv[g][0] - mean) * rs, gg.x, bb.x);
                o.y = fmaf((tv[g][1] - mean) * rs, gg.y, bb.y);
                o.z = fmaf((tv[g][2] - mean) * rs, gg.z, bb.z);
                o.w = fmaf((tv[g][3] - mean) * rs, gg.w, bb.w);
                *(float4*)(xd + g * 4) = o;
                ushort4 ob; ob.x = f2bf(o.x); ob.y = f2bf(o.y); ob.z = f2bf(o.z); ob.w = f2bf(o.w);
                *(ushort4*)(xb + g * 4) = ob;
            }
        }
    }
}

// ===================== fused FFN (FF1+FF2+LN2+LN3) =================
// v2: X (128x256 bf16 = 64KB) staged ONCE into fragment-order LDS in the
// prologue; the 128-slice main loop streams ONLY W (2 loads/wave/slice,
// uniform counted vmcnt(2)); W stays L2-resident. Hs 64KB, Wbuf 2x16KB.
__global__ __launch_bounds__(512, 2)
void ffn_fused(const unsigned short* __restrict__ X,   // [NVOX][256] bf16 (x_bf)
               const unsigned short* __restrict__ W1,  // [2048][256] bf16
               const unsigned short* __restrict__ W2,  // [256][2048] bf16
               const float* __restrict__ b1g,          // [2048]
               const float* __restrict__ b2g,          // [256]
               const float* __restrict__ xf,           // [NVOX][256] f32
               const float* __restrict__ prev,         // [NVOX][256] f32
               const float* __restrict__ lnG1, const float* __restrict__ lnB1,
               const float* __restrict__ lnG2, const float* __restrict__ lnB2,
               float* __restrict__ out) {
    // LDS: Xs 64KB | Wbuf 2x16KB | Hs 64KB = 160KB. ebuf aliases Xs (epilogue only).
    __shared__ alignas(16) char smem[163840];
    unsigned short* Xs   = (unsigned short*)smem;               // 64 subtiles x 512 u16
    unsigned short* Wbuf = (unsigned short*)(smem + 65536);     // 2 x 8192 u16
    char*           HsB  = smem + 98304;                        // 128x256 u16 (swizzled)
    float*          ebuf = (float*)smem;                        // epilogue alias (16x264)
    const int ES = 264;

    int tid = threadIdx.x;
    int wave = tid >> 6, lane = tid & 63;
    int wm = wave >> 2;          // 0..1: rows wm*64..+64
    int wn = wave & 3;           // 0..3: cols wn*64..+64
    int mBase = blockIdx.x * 128;
    int rr = lane & 15;
    int kq = (lane >> 4) * 8;
    int rbase = (lane >> 4) * 4;

    auto gll = [&](const unsigned short* g, unsigned short* l) {
        __builtin_amdgcn_global_load_lds((const AS1 void*)g, (AS3 void*)l, 16, 0, 0);
    };

    // ---- prologue: stage ALL of X in fragment order (wave w -> row-subtile w) ----
#pragma unroll
    for (int u = 0; u < 8; ++u)
        gll(X + (size_t)(mBase + wave * 16 + rr) * 256 + u * 32 + kq,
            Xs + (wave * 8 + u) * 512);

    // slice s (0..127): c=s>>4, half=(s>>3)&1, kt=s&7. W-only, 2 loads/wave.
    auto stage_slice = [&](int s) {
        int c = s >> 4, half = (s >> 3) & 1, kt = s & 7;
        unsigned short* wb = Wbuf + (s & 1) * 8192;
        if (half == 0) {
            gll(W1 + (size_t)(c * 256 + (wave * 2 + 0) * 16 + rr) * 256 + kt * 32 + kq,
                wb + (wave * 2 + 0) * 512);
            gll(W1 + (size_t)(c * 256 + (wave * 2 + 1) * 16 + rr) * 256 + kt * 32 + kq,
                wb + (wave * 2 + 1) * 512);
        } else {
            gll(W2 + (size_t)((wave * 2 + 0) * 16 + rr) * 2048 + c * 256 + kt * 32 + kq,
                wb + (wave * 2 + 0) * 512);
            gll(W2 + (size_t)((wave * 2 + 1) * 16 + rr) * 2048 + c * 256 + kt * 32 + kq,
                wb + (wave * 2 + 1) * 512);
        }
    };

    f32x4 yacc[4][4];
    const f32x4 zero = {0.f, 0.f, 0.f, 0.f};
#pragma unroll
    for (int m = 0; m < 4; m++)
#pragma unroll
        for (int n = 0; n < 4; n++) yacc[m][n] = zero;

    stage_slice(0);
    __syncthreads();   // drains X staging + slice 0 (vmcnt 0)

    for (int c = 0; c < 8; ++c) {
        f32x4 hacc[4][4];
#pragma unroll
        for (int m = 0; m < 4; m++)
#pragma unroll
            for (int n = 0; n < 4; n++) hacc[m][n] = zero;

        // ---- FF1: 8 W1-slices over K=256; A from resident Xs ----
#pragma unroll
        for (int kt = 0; kt < 8; ++kt) {
            int s = c * 16 + kt;
            stage_slice(s + 1);
            VMCNT2;
            __builtin_amdgcn_s_barrier();
            __builtin_amdgcn_sched_barrier(0);

            bf16x8 af[4], bf[4];
#pragma unroll
            for (int m = 0; m < 4; m++)
                af[m] = *(const bf16x8*)(Xs + ((wm * 4 + m) * 8 + kt) * 512 + lane * 8);
#pragma unroll
            for (int n = 0; n < 4; n++)
                bf[n] = *(const bf16x8*)(Wbuf + (s & 1) * 8192 + (wn * 4 + n) * 512 + lane * 8);
#pragma unroll
            for (int m = 0; m < 4; m++)
#pragma unroll
                for (int n = 0; n < 4; n++)
                    hacc[m][n] = __builtin_amdgcn_mfma_f32_16x16x32_bf16(af[m], bf[n], hacc[m][n], 0, 0, 0);

            __builtin_amdgcn_sched_barrier(0);
            __builtin_amdgcn_s_barrier();
        }

        // ---- write Hc = relu(hacc + b1) to swizzled LDS ----
        {
            float b1v[4];
#pragma unroll
            for (int n = 0; n < 4; n++)
                b1v[n] = b1g[c * 256 + wn * 64 + n * 16 + rr];
#pragma unroll
            for (int m = 0; m < 4; m++)
#pragma unroll
                for (int n = 0; n < 4; n++)
#pragma unroll
                    for (int r = 0; r < 4; r++) {
                        float v = fmaxf(hacc[m][n][r] + b1v[n], 0.f);
                        int row = wm * 64 + m * 16 + rbase + r;
                        int col = wn * 64 + n * 16 + rr;
                        unsigned byte = (unsigned)(row * 512 + col * 2) ^ ((row & 7) << 4);
                        *(unsigned short*)(HsB + byte) = f2bf(v);
                    }
            LGKM0;
            __builtin_amdgcn_s_barrier();
        }

        // ---- FF2: 8 W2-slices over Hc (K=256), accumulate y ----
#pragma unroll
        for (int kt = 0; kt < 8; ++kt) {
            int s = c * 16 + 8 + kt;
            if (s + 1 < 128) { stage_slice(s + 1); VMCNT2; }
            else { VMCNT0; }
            __builtin_amdgcn_s_barrier();
            __builtin_amdgcn_sched_barrier(0);

            bf16x8 af[4], bf[4];
#pragma unroll
            for (int m = 0; m < 4; m++) {
                int row = wm * 64 + m * 16 + rr;
                unsigned byte = (unsigned)(row * 512 + kt * 64 + (lane >> 4) * 16) ^ ((rr & 7) << 4);
                af[m] = *(const bf16x8*)(HsB + byte);
            }
#pragma unroll
            for (int n = 0; n < 4; n++)
                bf[n] = *(const bf16x8*)(Wbuf + (s & 1) * 8192 + (wn * 4 + n) * 512 + lane * 8);
#pragma unroll
            for (int m = 0; m < 4; m++)
#pragma unroll
                for (int n = 0; n < 4; n++)
                    yacc[m][n] = __builtin_amdgcn_mfma_f32_16x16x32_bf16(af[m], bf[n], yacc[m][n], 0, 0, 0);

            __builtin_amdgcn_sched_barrier(0);
            __builtin_amdgcn_s_barrier();
        }
    }

    // ---- epilogue: out = LN( LN(y + b2 + x) + prev ), 8 passes x 16 rows ----
    float b2v[4];
#pragma unroll
    for (int n = 0; n < 4; n++)
        b2v[n] = b2g[wn * 64 + n * 16 + rr];

    int erow = tid >> 5;              // 0..15
    int ec0  = (tid & 31) * 8;        // 0..248
#pragma unroll
    for (int p = 0; p < 8; ++p) {
        __syncthreads();
        if (wm == (p >> 2)) {
            const int m = p & 3;
#pragma unroll
            for (int n = 0; n < 4; ++n) {
                int lcol = wn * 64 + n * 16 + rr;
#pragma unroll
                for (int r = 0; r < 4; ++r)
                    ebuf[(rbase + r) * ES + lcol] = yacc[m][n][r] + b2v[n];
            }
        }
        __syncthreads();
        int grow = mBase + p * 16 + erow;

        float tv[8];
        float s1 = 0.f, s2 = 0.f;
        const float* xr = xf + (size_t)grow * 256 + ec0;
#pragma unroll
        for (int j = 0; j < 8; ++j) {
            float t = ebuf[erow * ES + ec0 + j] + xr[j];
            tv[j] = t; s1 += t; s2 += t * t;
        }
#pragma unroll
        for (int off = 1; off < 32; off <<= 1) { s1 += __shfl_xor(s1, off); s2 += __shfl_xor(s2, off); }
        float mean = s1 * (1.f/256.f);
        float var = fmaf(-mean, mean, s2 * (1.f/256.f));
        float rs = rsqrtf(var + 1e-5f);

        const float* pr = prev + (size_t)grow * 256 + ec0;
        float s3 = 0.f, s4 = 0.f;
#pragma unroll
        for (int j = 0; j < 8; ++j) {
            float u = fmaf((tv[j] - mean) * rs, lnG1[ec0 + j], lnB1[ec0 + j]) + pr[j];
            tv[j] = u; s3 += u; s4 += u * u;
        }
#pragma unroll
        for (int off = 1; off < 32; off <<= 1) { s3 += __shfl_xor(s3, off); s4 += __shfl_xor(s4, off); }
        float mean2 = s3 * (1.f/256.f);
        float var2 = fmaf(-mean2, mean2, s4 * (1.f/256.f));
        float rs2 = rsqrtf(var2 + 1e-5f);

        float* od = out + (size_t)grow * 256 + ec0;
#pragma unroll
        for (int g = 0; g < 2; ++g) {
            float4 o;
            o.x = fmaf((tv[g*4+0] - mean2) * rs2, lnG2[ec0 + g*4+0], lnB2[ec0 + g*4+0]);
            o.y = fmaf((tv[g*4+1] - mean2) * rs2, lnG2[ec0 + g*4+1], lnB2[ec0 + g*4+1]);
            o.z = fmaf((tv[g*4+2] - mean2) * rs2, lnG2[ec0 + g*4+2], lnB2[ec0 + g*4+2]);
            o.w = fmaf((tv[g*4+3] - mean2) * rs2, lnG2[ec0 + g*4+3], lnB2[ec0 + g*4+3]);
            *(float4*)(od + g * 4) = o;
        }
    }
}

// ======================= MFMA attention ===========================
__global__ __launch_bounds__(256)
void attn_mfma_kernel(const unsigned short* __restrict__ QK,
                      const unsigned short* __restrict__ V,
                      const unsigned char* __restrict__ mask,
                      unsigned short* __restrict__ ao) {
    int s = blockIdx.x, h = blockIdx.y;
    int tid = threadIdx.x;
    int wq = tid >> 6;
    int lane = tid & 63;

    __shared__ alignas(16) unsigned short Ks[128 * 40];
    __shared__ alignas(16) unsigned short Vt[32 * 136];
    __shared__ alignas(16) unsigned short Plds[4 * 4096];
    __shared__ unsigned char msk[SSZ];

#pragma unroll
    for (int it = 0; it < 2; it++) {
        int idx = tid + it * 256;
        int key = idx >> 2, dimoff = (idx & 3) * 8;
        bf16x8 kv = *(const bf16x8*)(QK + (size_t)(s * SSZ + key) * 512 + 256 + h * HDIM + dimoff);
        *(bf16x8*)(Ks + key * 40 + dimoff) = kv;
        u16x8 vv = *(const u16x8*)(V + (size_t)(s * SSZ + key) * DM + h * HDIM + dimoff);
#pragma unroll
        for (int j = 0; j < 8; j++) Vt[(dimoff + j) * 136 + key] = vv[j];
    }
    if (tid < SSZ) msk[tid] = mask[s * SSZ + tid];
    __syncthreads();

    int rr = lane & 15;
    int kq = (lane >> 4) * 8;
    const f32x4 zero = {0.f, 0.f, 0.f, 0.f};

    bf16x8 qa[2];
#pragma unroll
    for (int mt = 0; mt < 2; mt++)
        qa[mt] = *(const bf16x8*)(QK + (size_t)(s * SSZ + wq * 32 + mt * 16 + rr) * 512 + h * HDIM + kq);

    f32x4 S[2][8];
#pragma unroll
    for (int nt = 0; nt < 8; nt++) {
        bf16x8 kb = *(const bf16x8*)(Ks + (nt * 16 + rr) * 40 + kq);
#pragma unroll
        for (int mt = 0; mt < 2; mt++)
            S[mt][nt] = __builtin_amdgcn_mfma_f32_16x16x32_bf16(qa[mt], kb, zero, 0, 0, 0);
    }

    const float SCALE = 0.17677669529663687f;
    f32x4 rm[2];
#pragma unroll
    for (int mt = 0; mt < 2; mt++) { rm[mt].x = rm[mt].y = rm[mt].z = rm[mt].w = -1e30f; }
#pragma unroll
    for (int nt = 0; nt < 8; nt++) {
        bool mv = msk[nt * 16 + rr] != 0;
#pragma unroll
        for (int mt = 0; mt < 2; mt++) {
#pragma unroll
            for (int r = 0; r < 4; r++) {
                float v = mv ? -1e30f : S[mt][nt][r] * SCALE;
                S[mt][nt][r] = v;
                rm[mt][r] = fmaxf(rm[mt][r], v);
            }
        }
    }
#pragma unroll
    for (int off = 1; off < 16; off <<= 1) {
#pragma unroll
        for (int mt = 0; mt < 2; mt++)
#pragma unroll
            for (int r = 0; r < 4; r++)
                rm[mt][r] = fmaxf(rm[mt][r], __shfl_xor(rm[mt][r], off));
    }

    f32x4 rs[2];
#pragma unroll
    for (int mt = 0; mt < 2; mt++) { rs[mt] = zero; }
#pragma unroll
    for (int nt = 0; nt < 8; nt++)
#pragma unroll
        for (int mt = 0; mt < 2; mt++)
#pragma unroll
            for (int r = 0; r < 4; r++) {
                float p = __expf(S[mt][nt][r] - rm[mt][r]);
                S[mt][nt][r] = p;
                rs[mt][r] += p;
            }
#pragma unroll
    for (int off = 1; off < 16; off <<= 1) {
#pragma unroll
        for (int mt = 0; mt < 2; mt++)
#pragma unroll
            for (int r = 0; r < 4; r++)
                rs[mt][r] += __shfl_xor(rs[mt][r], off);
    }

    char* Pbase = (char*)Plds + wq * 8192;
#pragma unroll
    for (int nt = 0; nt < 8; nt++)
#pragma unroll
        for (int mt = 0; mt < 2; mt++)
#pragma unroll
            for (int r = 0; r < 4; r++) {
                int prow = mt * 16 + (lane >> 4) * 4 + r;
                int col  = nt * 16 + rr;
                unsigned addr = (unsigned)(prow * 256 + col * 2) ^ ((prow & 7) << 4);
                *(unsigned short*)(Pbase + addr) = f2bf(S[mt][nt][r]);
            }
    __syncthreads();

    f32x4 O[2][2];
#pragma unroll
    for (int mt = 0; mt < 2; mt++)
#pragma unroll
        for (int nd = 0; nd < 2; nd++) O[mt][nd] = zero;
#pragma unroll
    for (int kc = 0; kc < 4; kc++) {
        bf16x8 pa[2];
#pragma unroll
        for (int mt = 0; mt < 2; mt++) {
            int prow = mt * 16 + rr;
            unsigned addr = (unsigned)(prow * 256 + (kc * 32 + kq) * 2) ^ ((prow & 7) << 4);
            pa[mt] = *(const bf16x8*)(Pbase + addr);
        }
#pragma unroll
        for (int nd = 0; nd < 2; nd++) {
            bf16x8 vb = *(const bf16x8*)(Vt + (nd * 16 + rr) * 136 + kc * 32 + kq);
#pragma unroll
            for (int mt = 0; mt < 2; mt++)
                O[mt][nd] = __builtin_amdgcn_mfma_f32_16x16x32_bf16(pa[mt], vb, O[mt][nd], 0, 0, 0);
        }
    }

#pragma unroll
    for (int mt = 0; mt < 2; mt++) {
#pragma unroll
        for (int nd = 0; nd < 2; nd++) {
#pragma unroll
            for (int r = 0; r < 4; r++) {
                int row = s * SSZ + wq * 32 + mt * 16 + (lane >> 4) * 4 + r;
                int col = h * HDIM + nd * 16 + rr;
                ao[(size_t)row * DM + col] = f2bf(O[mt][nd][r] / rs[mt][r]);
            }
        }
    }
}

// ============================= launch =============================
extern "C" void kernel_launch(void* const* d_in, const int* in_sizes, int n_in,
                              void* d_out, int out_size, void* d_ws, size_t ws_size,
                              hipStream_t stream) {
    const float* src       = (const float*)d_in[0];
    const float* pos_embed = (const float*)d_in[1];
    const int*   inds_all  = (const int*)d_in[2];
    const unsigned char* masks_all = (const unsigned char*)d_in[3];
    const float* w_qkv = (const float*)d_in[4];
    const float* b_qkv = (const float*)d_in[5];
    const float* w_out = (const float*)d_in[6];
    const float* b_out = (const float*)d_in[7];
    const float* w_ff1 = (const float*)d_in[8];
    const float* b_ff1 = (const float*)d_in[9];
    const float* w_ff2 = (const float*)d_in[10];
    const float* b_ff2 = (const float*)d_in[11];
    const float* g_n1 = (const float*)d_in[12];
    const float* b_n1 = (const float*)d_in[13];
    const float* g_n2 = (const float*)d_in[14];
    const float* b_n2 = (const float*)d_in[15];
    const float* g_ln = (const float*)d_in[16];
    const float* b_ln = (const float*)d_in[17];
    float* out = (float*)d_out;

    const size_t NVF = (size_t)NVOX * DM;  // 16,777,216
    unsigned short* A = (unsigned short*)d_ws;   // NVF u16: qk_bf -> ao_bf
    unsigned short* B = A + NVF;                 // NVF u16: feat_bf -> x_bf
    unsigned short* C = B + NVF;                 // 2*NVF u16: [Q|K]
    unsigned short* D = C + 2 * NVF;             // NVF u16: V bf16
    float* F = (float*)(D + NVF);                // NVF f32: x
    unsigned short* wts = (unsigned short*)(F + NVF);
    const size_t SZ_QKV = (size_t)2 * 3 * DM * DM;
    const size_t SZ_WO  = (size_t)2 * DM * DM;
    const size_t SZ_FF1 = (size_t)2 * DFFN * DM;
    const size_t SZ_FF2 = (size_t)2 * DM * DFFN;
    unsigned short* wqkv_bf = wts;
    unsigned short* wo_bf   = wqkv_bf + SZ_QKV;
    unsigned short* wff1_bf = wo_bf + SZ_WO;
    unsigned short* wff2_bf = wff1_bf + SZ_FF1;

    cvt_bf16_kernel<<<512, 256, 0, stream>>>(w_qkv, wqkv_bf, (int)SZ_QKV);
    cvt_bf16_kernel<<<256, 256, 0, stream>>>(w_out, wo_bf, (int)SZ_WO);
    cvt_bf16_kernel<<<1024, 256, 0, stream>>>(w_ff1, wff1_bf, (int)SZ_FF1);
    cvt_bf16_kernel<<<1024, 256, 0, stream>>>(w_ff2, wff2_bf, (int)SZ_FF2);

    for (int i = 0; i < 2; i++) {
        const float* prev = (i == 0) ? src : out;
        const int* inds = inds_all + (size_t)i * 2 * SNUM * SSZ;
        const unsigned char* mask = masks_all + (size_t)i * 2 * SNUM * SSZ;
        const float* pos  = pos_embed + (size_t)i * NVF;
        const unsigned short* wqkv = wqkv_bf + (size_t)i * 3 * DM * DM;
        const unsigned short* wo   = wo_bf + (size_t)i * DM * DM;
        const unsigned short* wff1 = wff1_bf + (size_t)i * DFFN * DM;
        const unsigned short* wff2 = wff2_bf + (size_t)i * DM * DFFN;
        const float* bqkv = b_qkv + (size_t)i * 3 * DM;
        const float* bo   = b_out + (size_t)i * DM;
        const float* bff1 = b_ff1 + (size_t)i * DFFN;
        const float* bff2 = b_ff2 + (size_t)i * DM;

        gather_kernel<<<NVOX / 4, 256, 0, stream>>>(prev, pos, inds, A, B);

        // [Q|K] = qk @ [Wq;Wk]^T -> C (bf16)
        gemm_mfma256<0, false><<<dim3(NVOX / 256, 512 / 256), 512, 0, stream>>>(
            A, wqkv, bqkv, C, NVOX, 512, DM,
            nullptr, nullptr, nullptr, nullptr, nullptr);
        // V = feat @ Wv^T -> D (bf16)
        gemm_mfma256<0, false><<<dim3(NVOX / 256, 1), 512, 0, stream>>>(
            B, wqkv + (size_t)512 * DM, bqkv + 512, D, NVOX, DM, DM,
            nullptr, nullptr, nullptr, nullptr, nullptr);

        attn_mfma_kernel<<<dim3(SNUM, NH), 256, 0, stream>>>(C, D, mask, A);

        // Wo GEMM + fused LN1 scatter: x[v]=LN(a+prev[v]) -> F (f32) + B (bf16)
        gemm_mfma256<2, false><<<dim3(NVOX / 256, 1), 512, 0, stream>>>(
            A, wo, bo, F, NVOX, DM, DM,
            inds, prev, g_n1 + i * DM, b_n1 + i * DM, B);

        // fused FFN + LN2 + LN3 -> out
        ffn_fused<<<dim3(NVOX / 128), 512, 0, stream>>>(
            B, wff1, wff2, bff1, bff2, F, prev,
            g_n2 + i * DM, b_n2 + i * DM, g_ln + i * DM, b_ln + i * DM, out);
    }
}